// Round 1
// baseline (948.469 us; speedup 1.0000x reference)
//
#include <hip/hip_runtime.h>
#include <cstdint>
#include <cstddef>

#define NN 16   // neighbors
#define DI 32
#define DO 64

// ---------- tables ----------
__device__ __constant__ int c_INV[12][6] = {
  {0,1,2,3,4,5},{0,5,4,3,2,1},{4,3,0,5,2,1},{1,2,4,3,5,0},
  {3,5,2,0,4,1},{1,4,3,5,0,2},{4,0,3,1,2,5},{1,0,2,4,3,5},
  {4,1,2,5,0,3},{3,1,4,0,2,5},{2,1,4,5,3,0},{4,5,0,3,1,2}};
__device__ __constant__ int c_ROLL[5][6] = {
  {0,1,2,3,4,5},{0,2,3,4,5,1},{0,3,4,5,1,2},{0,4,5,1,2,3},{0,5,1,2,3,4}};
__device__ __constant__ float c_VS[12][3] = {
  {0.f, 0.5257311121f, 0.8506508084f},
  {0.f, 0.5257311121f, -0.8506508084f},
  {0.f, -0.5257311121f, 0.8506508084f},
  {0.f, -0.5257311121f, -0.8506508084f},
  {0.5257311121f, 0.8506508084f, 0.f},
  {0.5257311121f, -0.8506508084f, 0.f},
  {-0.5257311121f, 0.8506508084f, 0.f},
  {-0.5257311121f, -0.8506508084f, 0.f},
  {0.8506508084f, 0.f, 0.5257311121f},
  {0.8506508084f, 0.f, -0.5257311121f},
  {-0.8506508084f, 0.f, 0.5257311121f},
  {-0.8506508084f, 0.f, -0.5257311121f}};
__device__ __constant__ int c_C2V[6][2] = {{0,1},{6,7},{2,11},{4,9},{5,8},{3,10}};

// ---------- helpers ----------
__device__ inline unsigned short f2bf(float f) {
  unsigned int u = __float_as_uint(f);
  unsigned int r = (u + 0x7fffu + ((u >> 16) & 1u)) >> 16;   // RNE
  return (unsigned short)r;
}
__device__ inline float bf2f(unsigned short h) {
  return __uint_as_float(((unsigned int)h) << 16);
}

// build_sym scalar: W13[k][j] for raw 18-param row w
__device__ inline float sym13(const float* __restrict__ w, int k, int j) {
  if (k == 0)  return w[j == 0 ? 0 : 1];
  if (k == 1)  return w[j == 0 ? 2 : 3];
  if (k == 12) return w[j == 0 ? 4 : 5];
  int a = (k - 2) / 5, rr = (k - 2) % 5;
  return w[6 + a * 6 + c_ROLL[rr][j]];
}

// ---------- k0: weight expansion + fmT + feature_map passthrough ----------
// ws layout (floats):
//   A_g   @ 0        : 221184   (act weights, K-major: [ci/8][1152 row][ci%8], scaled by 0.5)
//   W2    @ 221184   : 1769472  ([k*12+r][d][ci])
//   Wc    @ 1990656  : 147456   ([r][d][ci])
//   fmT   @ 2138112  : 192*V    ([p][ci])
__global__ __launch_bounds__(256) void k0_expand(
    const float* __restrict__ W, const float* __restrict__ Wdir,
    const float* __restrict__ fm, float* __restrict__ ws,
    float* __restrict__ out_fm, int V) {
  int idx = blockIdx.x * 256 + threadIdx.x;
  if (idx < 221184) {
    int row = idx / 192, ci = idx % 192;
    int h = row / 144, k = (row / 12) % 12, r = row % 12;
    int c = ci / 6, i = ci % 6;
    float v = 0.5f * sym13(&Wdir[(h * 32 + c) * 18], k, c_INV[r][i]);
    ws[(ci >> 3) * (1152 * 8) + row * 8 + (ci & 7)] = v;
  } else if (idx < 1990656) {
    int e = idx - 221184;
    int kr = e / 12288, rem = e % 12288;
    int k = kr / 12, r = kr % 12, d = rem / 192, ci = rem % 192;
    int c = ci / 6, i = ci % 6;
    ws[idx] = sym13(&W[(d * 32 + c) * 18], k, c_INV[r][i]);
  } else if (idx < 2138112) {
    int e = idx - 1990656;
    int r = e / 12288, rem = e % 12288, d = rem / 192, ci = rem % 192;
    int c = ci / 6, i = ci % 6;
    ws[idx] = sym13(&W[(d * 32 + c) * 18], 12, c_INV[r][i]);
  } else {
    int e = idx - 2138112;
    if (e < 192 * V) {
      int p = e / 192, ci = e % 192, c = ci / 6, i = ci % 6;
      float v = fm[(c * V + p) * 6 + i];
      ws[idx] = v;                      // fmT[p*192+ci]
      out_fm[(c * V + p) * 6 + i] = v;  // passthrough output
    }
  }
}

// ---------- k1: directions + de6 + W_dim contraction -> cross[p][ci][n] ----------
__global__ __launch_bounds__(256) void k1_cross(
    const int* __restrict__ nbi, const float* __restrict__ verts,
    const float* __restrict__ fm, const float* __restrict__ Wdim,
    float* __restrict__ cross_g, int V) {
  __shared__ float in_s[NN * 33 * 6];
  __shared__ float wd_s[33 * 32];
  __shared__ int nb_s[NN];
  int p = blockIdx.x, t = threadIdx.x;
  if (t < NN) nb_s[t] = nbi[p * NN + t];
  for (int idx = t; idx < 1056; idx += 256) wd_s[idx] = Wdim[idx];
  __syncthreads();
  for (int idx = t; idx < NN * 32 * 6; idx += 256) {
    int n = idx / 192, rest = idx % 192, c = rest / 6, i = rest % 6;
    in_s[(n * 33 + c) * 6 + i] = fm[(c * V + nb_s[n]) * 6 + i];
  }
  if (t < NN) {
    int n = t, nb = nb_s[n];
    float px = verts[p * 3 + 0], py = verts[p * 3 + 1], pz = verts[p * 3 + 2];
    float dx = verts[nb * 3 + 0] - px, dy = verts[nb * 3 + 1] - py, dz = verts[nb * 3 + 2] - pz;
    float L = sqrtf(dx * dx + dy * dy + dz * dz);
    float inv = 1.0f / fmaxf(L, 1e-12f);
    dx *= inv; dy *= inv; dz *= inv;
    float de[12];
    #pragma unroll
    for (int v = 0; v < 12; ++v)
      de[v] = c_VS[v][0] * dx + c_VS[v][1] * dy + c_VS[v][2] * dz;
    #pragma unroll
    for (int j = 0; j < 6; ++j)
      in_s[(n * 33 + 32) * 6 + j] = fmaxf(de[c_C2V[j][0]], de[c_C2V[j][1]]);
  }
  __syncthreads();
  for (int idx = t; idx < 3072; idx += 256) {
    int ci = idx >> 4, n = idx & 15;
    int o = ci / 6, i = ci % 6;
    float s = 0.f;
    #pragma unroll
    for (int c = 0; c <= 32; ++c)
      s = fmaf(wd_s[c * 32 + o], in_s[(n * 33 + c) * 6 + i], s);
    cross_g[(size_t)p * 3072 + idx] = s;
  }
}

// ---------- k2: act GEMM + softmax + n-contraction -> nfm (bf16) ----------
// LDS: A_ch float[8][512] | cross_N float[16][192] | act_s ushort[1152][16]  == 65536 B
__global__ __launch_bounds__(256) void k2_main(
    const float* __restrict__ A_g, const float* __restrict__ cross_g,
    unsigned short* __restrict__ nfm, int V) {
  extern __shared__ float smem[];
  float* A_ch = smem;                                   // 4096 floats
  float* cross_N = smem + 4096;                         // 3072 floats [n][ci]
  unsigned short* act_s = (unsigned short*)(smem + 7168); // 18432 ushort [row][n]
  int p = blockIdx.x, t = threadIdx.x;

  for (int idx = t; idx < 3072; idx += 256) {
    int ci = idx >> 4, n = idx & 15;
    cross_N[n * 192 + ci] = cross_g[(size_t)p * 3072 + idx];
  }
  __syncthreads();

  int rq = t & 63, nq = t >> 6;
  int n0 = nq * 4;

  for (int chunk = 0; chunk < 3; ++chunk) {
    int rowBase = chunk * 512;
    int rows = min(512, 1152 - rowBase);
    bool lo = (rq * 4 < rows);
    bool hi = (256 + rq * 4 < rows);
    float accL[4][4] = {{0.f}}, accH[4][4] = {{0.f}};
    for (int kkc = 0; kkc < 24; ++kkc) {
      for (int flat = t; flat < rows * 2; flat += 256) {
        int rl = flat >> 1, kq = flat & 1;
        const float4 v = *(const float4*)&A_g[kkc * 9216 + (rowBase + rl) * 8 + kq * 4];
        A_ch[(kq * 4 + 0) * 512 + rl] = v.x;
        A_ch[(kq * 4 + 1) * 512 + rl] = v.y;
        A_ch[(kq * 4 + 2) * 512 + rl] = v.z;
        A_ch[(kq * 4 + 3) * 512 + rl] = v.w;
      }
      __syncthreads();
      int kb = kkc * 8;
      if (lo || hi) {
        #pragma unroll
        for (int kk = 0; kk < 8; ++kk) {
          float x4[4];
          #pragma unroll
          for (int j = 0; j < 4; ++j) x4[j] = cross_N[(n0 + j) * 192 + kb + kk];
          if (lo) {
            float4 a = *(const float4*)&A_ch[kk * 512 + rq * 4];
            float a4[4] = {a.x, a.y, a.z, a.w};
            #pragma unroll
            for (int i = 0; i < 4; ++i)
              #pragma unroll
              for (int j = 0; j < 4; ++j)
                accL[i][j] = fmaf(a4[i], x4[j], accL[i][j]);
          }
          if (hi) {
            float4 a = *(const float4*)&A_ch[kk * 512 + 256 + rq * 4];
            float a4[4] = {a.x, a.y, a.z, a.w};
            #pragma unroll
            for (int i = 0; i < 4; ++i)
              #pragma unroll
              for (int j = 0; j < 4; ++j)
                accH[i][j] = fmaf(a4[i], x4[j], accH[i][j]);
          }
        }
      }
      __syncthreads();
    }
    if (lo) {
      #pragma unroll
      for (int i = 0; i < 4; ++i)
        #pragma unroll
        for (int j = 0; j < 4; ++j)
          act_s[(rowBase + rq * 4 + i) * 16 + n0 + j] = f2bf(accL[i][j]);
    }
    if (hi) {
      #pragma unroll
      for (int i = 0; i < 4; ++i)
        #pragma unroll
        for (int j = 0; j < 4; ++j)
          act_s[(rowBase + 256 + rq * 4 + i) * 16 + n0 + j] = f2bf(accH[i][j]);
    }
  }
  __syncthreads();

  // softmax over n (16-lane groups)
  for (int it = 0; it < 72; ++it) {
    int row = it * 16 + (t >> 4), n = t & 15;
    float v = bf2f(act_s[row * 16 + n]);
    float m = v;
    #pragma unroll
    for (int mask = 8; mask; mask >>= 1) m = fmaxf(m, __shfl_xor(m, mask, 16));
    float e = __expf(v - m);
    float s = e;
    #pragma unroll
    for (int mask = 8; mask; mask >>= 1) s += __shfl_xor(s, mask, 16);
    act_s[row * 16 + n] = f2bf(e / s);
  }
  __syncthreads();

  // nfm[p][ (k*12+r)*192 + c*6+i ] = sum_n act[(h*12+k)*12+r][n] * cross[n][c*6+i]
  size_t obase = (size_t)p * 27648;
  for (int it = 0; it < 108; ++it) {
    int idx = it * 256 + t;
    int kr = idx / 192, cc = idx % 192;
    int row = (cc / 24) * 144 + kr;
    float s = 0.f;
    #pragma unroll
    for (int n = 0; n < NN; ++n)
      s = fmaf(bf2f(act_s[row * 16 + n]), cross_N[n * 192 + cc], s);
    nfm[obase + idx] = f2bf(s);
  }
}

// ---------- k3: feat GEMMs + center -> ka12[r][d][p] ----------
__global__ __launch_bounds__(256) void k3_feat(
    const float* __restrict__ W2, const float* __restrict__ Wc,
    const float* __restrict__ fmT, const unsigned short* __restrict__ nfm,
    float* __restrict__ ka12, int V) {
  __shared__ float A_s[64 * 68];  // [kk][d]
  __shared__ float B_s[64 * 36];  // [kk][p]
  int pb = blockIdx.x, r = blockIdx.y, t = threadIdx.x;
  int d0 = (t & 15) * 4, p0 = (t >> 4) * 2;
  float acc[4][2] = {{0.f}};
  for (int kb = 0; kb <= 12; ++kb) {
    const float* Abase = (kb < 12) ? &W2[(size_t)(kb * 12 + r) * 64 * 192]
                                   : &Wc[(size_t)r * 64 * 192];
    for (int kkc = 0; kkc < 3; ++kkc) {
      {
        int ci_l = (t & 15) * 4;
        #pragma unroll
        for (int dd = 0; dd < 4; ++dd) {
          int d_l = (t >> 4) + dd * 16;
          float4 v = *(const float4*)&Abase[d_l * 192 + kkc * 64 + ci_l];
          A_s[(ci_l + 0) * 68 + d_l] = v.x;
          A_s[(ci_l + 1) * 68 + d_l] = v.y;
          A_s[(ci_l + 2) * 68 + d_l] = v.z;
          A_s[(ci_l + 3) * 68 + d_l] = v.w;
        }
      }
      if (kb < 12) {
        int p_l = t >> 3, kq = t & 7;
        const unsigned short* src =
            &nfm[(size_t)(pb * 32 + p_l) * 27648 + (size_t)(kb * 12 + r) * 192 + kkc * 64 + kq * 8];
        uint4 u = *(const uint4*)src;
        unsigned int w[4] = {u.x, u.y, u.z, u.w};
        #pragma unroll
        for (int q = 0; q < 4; ++q) {
          B_s[(kq * 8 + 2 * q + 0) * 36 + p_l] = bf2f((unsigned short)(w[q] & 0xffffu));
          B_s[(kq * 8 + 2 * q + 1) * 36 + p_l] = bf2f((unsigned short)(w[q] >> 16));
        }
      } else {
        #pragma unroll
        for (int pp = 0; pp < 2; ++pp) {
          int p_l = (t >> 4) + pp * 16, ci2 = (t & 15) * 4;
          float4 v = *(const float4*)&fmT[(size_t)(pb * 32 + p_l) * 192 + kkc * 64 + ci2];
          B_s[(ci2 + 0) * 36 + p_l] = v.x;
          B_s[(ci2 + 1) * 36 + p_l] = v.y;
          B_s[(ci2 + 2) * 36 + p_l] = v.z;
          B_s[(ci2 + 3) * 36 + p_l] = v.w;
        }
      }
      __syncthreads();
      #pragma unroll 8
      for (int kk = 0; kk < 64; ++kk) {
        float4 a = *(const float4*)&A_s[kk * 68 + d0];
        float bx = B_s[kk * 36 + p0];
        float by = B_s[kk * 36 + p0 + 1];
        acc[0][0] = fmaf(a.x, bx, acc[0][0]); acc[0][1] = fmaf(a.x, by, acc[0][1]);
        acc[1][0] = fmaf(a.y, bx, acc[1][0]); acc[1][1] = fmaf(a.y, by, acc[1][1]);
        acc[2][0] = fmaf(a.z, bx, acc[2][0]); acc[2][1] = fmaf(a.z, by, acc[2][1]);
        acc[3][0] = fmaf(a.w, bx, acc[3][0]); acc[3][1] = fmaf(a.w, by, acc[3][1]);
      }
      __syncthreads();
    }
  }
  int pg = pb * 32 + p0;
  #pragma unroll
  for (int i = 0; i < 4; ++i)
    #pragma unroll
    for (int j = 0; j < 2; ++j)
      ka12[(size_t)(r * 64 + d0 + i) * V + pg + j] = acc[i][j];
}

// ---------- k4: c2v max -> ka output ----------
__global__ __launch_bounds__(256) void k4_final(
    const float* __restrict__ ka12, float* __restrict__ out, int V) {
  int idx = blockIdx.x * 256 + threadIdx.x;
  int total = DO * V * 6;
  if (idx >= total) return;
  int j = idx % 6, rem = idx / 6;
  int p = rem % V, d = rem / V;
  size_t base = (size_t)d * V + p;
  float a = ka12[(size_t)c_C2V[j][0] * 64 * V + base];
  float b = ka12[(size_t)c_C2V[j][1] * 64 * V + base];
  out[idx] = fmaxf(a, b);
}

// ---------- host ----------
extern "C" void kernel_launch(void* const* d_in, const int* in_sizes, int n_in,
                              void* d_out, int out_size, void* d_ws, size_t ws_size,
                              hipStream_t stream) {
  const int* nbi = (const int*)d_in[0];
  const float* verts = (const float*)d_in[1];
  const float* fm = (const float*)d_in[2];
  const float* Wdim = (const float*)d_in[3];
  const float* W = (const float*)d_in[4];
  const float* Wdir = (const float*)d_in[5];
  float* out = (float*)d_out;
  float* ws = (float*)d_ws;
  int V = in_sizes[0] / NN;   // 2048

  float* A_g = ws;                                  // 221184
  float* W2 = ws + 221184;                          // 1769472
  float* Wc = ws + 1990656;                         // 147456
  float* fmT = ws + 2138112;                        // 192*V
  float* crossg = fmT + (size_t)192 * V;            // 3072*V
  float* ka12 = crossg + (size_t)3072 * V;          // 768*V
  unsigned short* nfm = (unsigned short*)(ka12 + (size_t)768 * V);  // 27648*V bf16

  int n0 = 2138112 + 192 * V;
  k0_expand<<<(n0 + 255) / 256, 256, 0, stream>>>(W, Wdir, fm, ws, out + (size_t)DO * V * 6, V);
  k1_cross<<<V, 256, 0, stream>>>(nbi, verts, fm, Wdim, crossg, V);
  k2_main<<<V, 256, 65536, stream>>>(A_g, crossg, nfm, V);
  k3_feat<<<dim3(V / 32, 12), 256, 0, stream>>>(W2, Wc, fmT, nfm, ka12, V);
  k4_final<<<(DO * V * 6 + 255) / 256, 256, 0, stream>>>(ka12, out, V);
}

// Round 2
// 499.308 us; speedup vs baseline: 1.8996x; 1.8996x over previous
//
#include <hip/hip_runtime.h>
#include <cstdint>
#include <cstddef>

#define NN 16   // neighbors
#define DI 32
#define DO 64

typedef short bf16x8 __attribute__((ext_vector_type(8)));
typedef float f32x4 __attribute__((ext_vector_type(4)));

// ---------- tables ----------
__device__ __constant__ int c_INV[12][6] = {
  {0,1,2,3,4,5},{0,5,4,3,2,1},{4,3,0,5,2,1},{1,2,4,3,5,0},
  {3,5,2,0,4,1},{1,4,3,5,0,2},{4,0,3,1,2,5},{1,0,2,4,3,5},
  {4,1,2,5,0,3},{3,1,4,0,2,5},{2,1,4,5,3,0},{4,5,0,3,1,2}};
__device__ __constant__ int c_ROLL[5][6] = {
  {0,1,2,3,4,5},{0,2,3,4,5,1},{0,3,4,5,1,2},{0,4,5,1,2,3},{0,5,1,2,3,4}};
__device__ __constant__ float c_VS[12][3] = {
  {0.f, 0.5257311121f, 0.8506508084f},
  {0.f, 0.5257311121f, -0.8506508084f},
  {0.f, -0.5257311121f, 0.8506508084f},
  {0.f, -0.5257311121f, -0.8506508084f},
  {0.5257311121f, 0.8506508084f, 0.f},
  {0.5257311121f, -0.8506508084f, 0.f},
  {-0.5257311121f, 0.8506508084f, 0.f},
  {-0.5257311121f, -0.8506508084f, 0.f},
  {0.8506508084f, 0.f, 0.5257311121f},
  {0.8506508084f, 0.f, -0.5257311121f},
  {-0.8506508084f, 0.f, 0.5257311121f},
  {-0.8506508084f, 0.f, -0.5257311121f}};
__device__ __constant__ int c_C2V[6][2] = {{0,1},{6,7},{2,11},{4,9},{5,8},{3,10}};

// ---------- helpers ----------
__device__ inline unsigned short f2bf(float f) {
  unsigned int u = __float_as_uint(f);
  unsigned int r = (u + 0x7fffu + ((u >> 16) & 1u)) >> 16;   // RNE
  return (unsigned short)r;
}
__device__ inline float bf2f(unsigned short h) {
  return __uint_as_float(((unsigned int)h) << 16);
}

__device__ inline float sym13(const float* __restrict__ w, int k, int j) {
  if (k == 0)  return w[j == 0 ? 0 : 1];
  if (k == 1)  return w[j == 0 ? 2 : 3];
  if (k == 12) return w[j == 0 ? 4 : 5];
  int a = (k - 2) / 5, rr = (k - 2) % 5;
  return w[6 + a * 6 + c_ROLL[rr][j]];
}

// ---------- k0: weight expansion (A in bf16) + fmT + passthrough ----------
__global__ __launch_bounds__(256) void k0_expand(
    const float* __restrict__ W, const float* __restrict__ Wdir,
    const float* __restrict__ fm,
    unsigned short* __restrict__ A_bf,   // [1152][192] bf16, scaled by 0.5
    float* __restrict__ W2,              // [144][64][192]
    float* __restrict__ Wc,              // [12][64][192]
    float* __restrict__ fmT,             // [V][192]
    float* __restrict__ out_fm, int V) {
  int idx = blockIdx.x * 256 + threadIdx.x;
  if (idx < 221184) {
    int row = idx / 192, ci = idx % 192;
    int h = row / 144, k = (row / 12) % 12, r = row % 12;
    int c = ci / 6, i = ci % 6;
    A_bf[idx] = f2bf(0.5f * sym13(&Wdir[(h * 32 + c) * 18], k, c_INV[r][i]));
  } else if (idx < 1990656) {
    int e = idx - 221184;
    int kr = e / 12288, rem = e % 12288;
    int k = kr / 12, r = kr % 12, d = rem / 192, ci = rem % 192;
    int c = ci / 6, i = ci % 6;
    W2[e] = sym13(&W[(d * 32 + c) * 18], k, c_INV[r][i]);
  } else if (idx < 2138112) {
    int e = idx - 1990656;
    int r = e / 12288, rem = e % 12288, d = rem / 192, ci = rem % 192;
    int c = ci / 6, i = ci % 6;
    Wc[e] = sym13(&W[(d * 32 + c) * 18], 12, c_INV[r][i]);
  } else {
    int e = idx - 2138112;
    if (e < 192 * V) {
      int p = e / 192, ci = e % 192, c = ci / 6, i = ci % 6;
      float v = fm[(c * V + p) * 6 + i];
      fmT[e] = v;
      out_fm[(c * V + p) * 6 + i] = v;
    }
  }
}

// ---------- k1: directions + de6 + W_dim -> cross_bf [p][n][ci] bf16 ----------
__global__ __launch_bounds__(256) void k1_cross(
    const int* __restrict__ nbi, const float* __restrict__ verts,
    const float* __restrict__ fm, const float* __restrict__ Wdim,
    unsigned short* __restrict__ cross_bf, int V) {
  __shared__ float in_s[NN * 33 * 6];
  __shared__ float wd_s[33 * 32];
  __shared__ int nb_s[NN];
  int p = blockIdx.x, t = threadIdx.x;
  if (t < NN) nb_s[t] = nbi[p * NN + t];
  for (int idx = t; idx < 1056; idx += 256) wd_s[idx] = Wdim[idx];
  __syncthreads();
  for (int idx = t; idx < NN * 32 * 6; idx += 256) {
    int n = idx / 192, rest = idx % 192, c = rest / 6, i = rest % 6;
    in_s[(n * 33 + c) * 6 + i] = fm[(c * V + nb_s[n]) * 6 + i];
  }
  if (t < NN) {
    int n = t, nb = nb_s[n];
    float px = verts[p * 3 + 0], py = verts[p * 3 + 1], pz = verts[p * 3 + 2];
    float dx = verts[nb * 3 + 0] - px, dy = verts[nb * 3 + 1] - py, dz = verts[nb * 3 + 2] - pz;
    float L = sqrtf(dx * dx + dy * dy + dz * dz);
    float inv = 1.0f / fmaxf(L, 1e-12f);
    dx *= inv; dy *= inv; dz *= inv;
    float de[12];
    #pragma unroll
    for (int v = 0; v < 12; ++v)
      de[v] = c_VS[v][0] * dx + c_VS[v][1] * dy + c_VS[v][2] * dz;
    #pragma unroll
    for (int j = 0; j < 6; ++j)
      in_s[(n * 33 + 32) * 6 + j] = fmaxf(de[c_C2V[j][0]], de[c_C2V[j][1]]);
  }
  __syncthreads();
  // write packed bf16 pairs: cross_bf[p][n][ci], ci pairs per uint
  unsigned int* dst = (unsigned int*)(cross_bf + (size_t)p * 3072);
  for (int idx = t; idx < 1536; idx += 256) {
    int n = idx / 96, cp2 = idx % 96;
    int ci0 = cp2 * 2, ci1 = ci0 + 1;
    int o0 = ci0 / 6, i0 = ci0 % 6;
    int o1 = ci1 / 6, i1 = ci1 % 6;
    float s0 = 0.f, s1 = 0.f;
    #pragma unroll
    for (int c = 0; c <= 32; ++c) {
      float f0 = in_s[(n * 33 + c) * 6 + i0];
      float f1 = in_s[(n * 33 + c) * 6 + i1];
      s0 = fmaf(wd_s[c * 32 + o0], f0, s0);
      s1 = fmaf(wd_s[c * 32 + o1], f1, s1);
    }
    dst[idx] = (unsigned int)f2bf(s0) | ((unsigned int)f2bf(s1) << 16);
  }
}

// ---------- k2: MFMA act GEMM + in-register softmax + nfm ----------
// block = 4 vertices, 256 threads (4 waves). LDS 43008 B -> >=2 blocks/CU.
__global__ __launch_bounds__(256) void k2_main(
    const unsigned short* __restrict__ A_bf,
    const unsigned short* __restrict__ cross_bf,
    unsigned short* __restrict__ nfm, int V) {
  __shared__ unsigned short B_lds[4][16][200];  // [p][n][ci], +8 pad: 2-way banks
  __shared__ float act_s[4][4][16][17];         // [wave][p][row][n], stride 17
  int t = threadIdx.x;
  int w = t >> 6, lane = t & 63;
  int quad = lane >> 4, col = lane & 15;
  int p0 = blockIdx.x * 4;

  for (int i = t; i < 1536; i += 256) {
    int e = i * 8;
    int p = e / 3072, off = e % 3072;
    int n = off / 192, ci = off % 192;
    *(uint4*)&B_lds[p][n][ci] =
        *(const uint4*)(cross_bf + (size_t)(p0 + p) * 3072 + off);
  }
  __syncthreads();

  int pl = quad, rl = col;  // nfm-phase lane roles: 64 lanes <-> 4p x 16 rows

  for (int rt = w; rt < 72; rt += 4) {          // 18 tiles per wave, uniform
    int R0 = rt * 16;
    int h = rt / 9;                             // 9 tiles per head
    int krbase = R0 - h * 144;
    f32x4 acc[4];
    #pragma unroll
    for (int p = 0; p < 4; ++p) acc[p] = (f32x4){0.f, 0.f, 0.f, 0.f};
    const unsigned short* Abase = A_bf + (size_t)(R0 + col) * 192 + quad * 8;
    #pragma unroll
    for (int ks = 0; ks < 6; ++ks) {
      bf16x8 af = *(const bf16x8*)(Abase + ks * 32);
      #pragma unroll
      for (int p = 0; p < 4; ++p) {
        bf16x8 bfr = *(const bf16x8*)&B_lds[p][col][ks * 32 + quad * 8];
        acc[p] = __builtin_amdgcn_mfma_f32_16x16x32_bf16(af, bfr, acc[p], 0, 0, 0);
      }
    }
    // softmax over n: C layout col(n)=lane&15, row=quad*4+reg -> shfl width 16
    #pragma unroll
    for (int p = 0; p < 4; ++p) {
      #pragma unroll
      for (int r = 0; r < 4; ++r) {
        float v = acc[p][r];
        float m = v;
        #pragma unroll
        for (int mk = 8; mk; mk >>= 1) m = fmaxf(m, __shfl_xor(m, mk, 16));
        float e = __expf(v - m);
        float s = e;
        #pragma unroll
        for (int mk = 8; mk; mk >>= 1) s += __shfl_xor(s, mk, 16);
        acc[p][r] = e / s;
      }
    }
    #pragma unroll
    for (int p = 0; p < 4; ++p)
      #pragma unroll
      for (int r = 0; r < 4; ++r)
        act_s[w][p][quad * 4 + r][col] = acc[p][r];
    __syncthreads();
    // nfm: each lane one (p,row): out[ci in h-slice] = sum_n act*cross
    float av[16];
    #pragma unroll
    for (int n = 0; n < 16; ++n) av[n] = act_s[w][pl][rl][n];
    float o[24];
    #pragma unroll
    for (int c = 0; c < 24; ++c) o[c] = 0.f;
    int h24 = h * 24;
    #pragma unroll
    for (int n = 0; n < 16; ++n) {
      float a = av[n];
      const uint4* cp = (const uint4*)&B_lds[pl][n][h24];  // broadcast reads
      uint4 u0 = cp[0], u1 = cp[1], u2 = cp[2];
      unsigned int uu[12] = {u0.x, u0.y, u0.z, u0.w, u1.x, u1.y, u1.z, u1.w,
                             u2.x, u2.y, u2.z, u2.w};
      #pragma unroll
      for (int q = 0; q < 12; ++q) {
        o[2 * q]     = fmaf(a, __uint_as_float(uu[q] << 16), o[2 * q]);
        o[2 * q + 1] = fmaf(a, __uint_as_float(uu[q] & 0xffff0000u), o[2 * q + 1]);
      }
    }
    unsigned int pk[12];
    #pragma unroll
    for (int q = 0; q < 12; ++q)
      pk[q] = (unsigned int)f2bf(o[2 * q]) | ((unsigned int)f2bf(o[2 * q + 1]) << 16);
    size_t ob = ((size_t)(p0 + pl) * 144 + (size_t)(krbase + rl)) * 192 + h24;
    uint4* dst = (uint4*)(nfm + ob);
    dst[0] = make_uint4(pk[0], pk[1], pk[2], pk[3]);
    dst[1] = make_uint4(pk[4], pk[5], pk[6], pk[7]);
    dst[2] = make_uint4(pk[8], pk[9], pk[10], pk[11]);
    __syncthreads();
  }
}

// ---------- k3: feat GEMMs + center -> ka12[r][d][p] ----------
__global__ __launch_bounds__(256) void k3_feat(
    const float* __restrict__ W2, const float* __restrict__ Wc,
    const float* __restrict__ fmT, const unsigned short* __restrict__ nfm,
    float* __restrict__ ka12, int V) {
  __shared__ float A_s[64 * 68];
  __shared__ float B_s[64 * 36];
  int pb = blockIdx.x, r = blockIdx.y, t = threadIdx.x;
  int d0 = (t & 15) * 4, p0 = (t >> 4) * 2;
  float acc[4][2] = {{0.f}};
  for (int kb = 0; kb <= 12; ++kb) {
    const float* Abase = (kb < 12) ? &W2[(size_t)(kb * 12 + r) * 64 * 192]
                                   : &Wc[(size_t)r * 64 * 192];
    for (int kkc = 0; kkc < 3; ++kkc) {
      {
        int ci_l = (t & 15) * 4;
        #pragma unroll
        for (int dd = 0; dd < 4; ++dd) {
          int d_l = (t >> 4) + dd * 16;
          float4 v = *(const float4*)&Abase[d_l * 192 + kkc * 64 + ci_l];
          A_s[(ci_l + 0) * 68 + d_l] = v.x;
          A_s[(ci_l + 1) * 68 + d_l] = v.y;
          A_s[(ci_l + 2) * 68 + d_l] = v.z;
          A_s[(ci_l + 3) * 68 + d_l] = v.w;
        }
      }
      if (kb < 12) {
        int p_l = t >> 3, kq = t & 7;
        const unsigned short* src =
            &nfm[(size_t)(pb * 32 + p_l) * 27648 + (size_t)(kb * 12 + r) * 192 + kkc * 64 + kq * 8];
        uint4 u = *(const uint4*)src;
        unsigned int wv[4] = {u.x, u.y, u.z, u.w};
        #pragma unroll
        for (int q = 0; q < 4; ++q) {
          B_s[(kq * 8 + 2 * q + 0) * 36 + p_l] = bf2f((unsigned short)(wv[q] & 0xffffu));
          B_s[(kq * 8 + 2 * q + 1) * 36 + p_l] = bf2f((unsigned short)(wv[q] >> 16));
        }
      } else {
        #pragma unroll
        for (int pp = 0; pp < 2; ++pp) {
          int p_l = (t >> 4) + pp * 16, ci2 = (t & 15) * 4;
          float4 v = *(const float4*)&fmT[(size_t)(pb * 32 + p_l) * 192 + kkc * 64 + ci2];
          B_s[(ci2 + 0) * 36 + p_l] = v.x;
          B_s[(ci2 + 1) * 36 + p_l] = v.y;
          B_s[(ci2 + 2) * 36 + p_l] = v.z;
          B_s[(ci2 + 3) * 36 + p_l] = v.w;
        }
      }
      __syncthreads();
      #pragma unroll 8
      for (int kk = 0; kk < 64; ++kk) {
        float4 a = *(const float4*)&A_s[kk * 68 + d0];
        float bx = B_s[kk * 36 + p0];
        float by = B_s[kk * 36 + p0 + 1];
        acc[0][0] = fmaf(a.x, bx, acc[0][0]); acc[0][1] = fmaf(a.x, by, acc[0][1]);
        acc[1][0] = fmaf(a.y, bx, acc[1][0]); acc[1][1] = fmaf(a.y, by, acc[1][1]);
        acc[2][0] = fmaf(a.z, bx, acc[2][0]); acc[2][1] = fmaf(a.z, by, acc[2][1]);
        acc[3][0] = fmaf(a.w, bx, acc[3][0]); acc[3][1] = fmaf(a.w, by, acc[3][1]);
      }
      __syncthreads();
    }
  }
  int pg = pb * 32 + p0;
  #pragma unroll
  for (int i = 0; i < 4; ++i)
    #pragma unroll
    for (int j = 0; j < 2; ++j)
      ka12[(size_t)(r * 64 + d0 + i) * V + pg + j] = acc[i][j];
}

// ---------- k4: c2v max -> ka output ----------
__global__ __launch_bounds__(256) void k4_final(
    const float* __restrict__ ka12, float* __restrict__ out, int V) {
  int idx = blockIdx.x * 256 + threadIdx.x;
  int total = DO * V * 6;
  if (idx >= total) return;
  int j = idx % 6, rem = idx / 6;
  int p = rem % V, d = rem / V;
  size_t base = (size_t)d * V + p;
  float a = ka12[(size_t)c_C2V[j][0] * 64 * V + base];
  float b = ka12[(size_t)c_C2V[j][1] * 64 * V + base];
  out[idx] = fmaxf(a, b);
}

// ---------- host ----------
extern "C" void kernel_launch(void* const* d_in, const int* in_sizes, int n_in,
                              void* d_out, int out_size, void* d_ws, size_t ws_size,
                              hipStream_t stream) {
  const int* nbi = (const int*)d_in[0];
  const float* verts = (const float*)d_in[1];
  const float* fm = (const float*)d_in[2];
  const float* Wdim = (const float*)d_in[3];
  const float* W = (const float*)d_in[4];
  const float* Wdir = (const float*)d_in[5];
  float* out = (float*)d_out;
  float* ws = (float*)d_ws;
  int V = in_sizes[0] / NN;   // 2048

  unsigned short* A_bf = (unsigned short*)ws;          // 221184 ush = 110592 f32
  float* W2 = ws + 110592;                             // 1769472
  float* Wc = ws + 1880064;                            // 147456
  float* fmT = ws + 2027520;                           // 192*V
  unsigned short* cross_bf = (unsigned short*)(ws + 2027520 + (size_t)192 * V);  // 3072*V ush
  float* ka12 = ws + 2027520 + (size_t)192 * V + (size_t)1536 * V;               // 768*V
  unsigned short* nfm = (unsigned short*)(ka12 + (size_t)768 * V);               // 27648*V ush

  int n0 = 2138112 + 192 * V;
  k0_expand<<<(n0 + 255) / 256, 256, 0, stream>>>(W, Wdir, fm, A_bf, W2, Wc, fmT,
                                                  out + (size_t)DO * V * 6, V);
  k1_cross<<<V, 256, 0, stream>>>(nbi, verts, fm, Wdim, cross_bf, V);
  k2_main<<<V / 4, 256, 0, stream>>>(A_bf, cross_bf, nfm, V);
  k3_feat<<<dim3(V / 32, 12), 256, 0, stream>>>(W2, Wc, fmT, nfm, ka12, V);
  k4_final<<<(DO * V * 6 + 255) / 256, 256, 0, stream>>>(ka12, out, V);
}

// Round 3
// 337.632 us; speedup vs baseline: 2.8092x; 1.4789x over previous
//
#include <hip/hip_runtime.h>
#include <cstdint>
#include <cstddef>

#define NN 16   // neighbors
#define DI 32
#define DO 64

typedef short bf16x8 __attribute__((ext_vector_type(8)));
typedef float f32x4 __attribute__((ext_vector_type(4)));

// ---------- tables ----------
__device__ __constant__ int c_INV[12][6] = {
  {0,1,2,3,4,5},{0,5,4,3,2,1},{4,3,0,5,2,1},{1,2,4,3,5,0},
  {3,5,2,0,4,1},{1,4,3,5,0,2},{4,0,3,1,2,5},{1,0,2,4,3,5},
  {4,1,2,5,0,3},{3,1,4,0,2,5},{2,1,4,5,3,0},{4,5,0,3,1,2}};
__device__ __constant__ int c_ROLL[5][6] = {
  {0,1,2,3,4,5},{0,2,3,4,5,1},{0,3,4,5,1,2},{0,4,5,1,2,3},{0,5,1,2,3,4}};
__device__ __constant__ float c_VS[12][3] = {
  {0.f, 0.5257311121f, 0.8506508084f},
  {0.f, 0.5257311121f, -0.8506508084f},
  {0.f, -0.5257311121f, 0.8506508084f},
  {0.f, -0.5257311121f, -0.8506508084f},
  {0.5257311121f, 0.8506508084f, 0.f},
  {0.5257311121f, -0.8506508084f, 0.f},
  {-0.5257311121f, 0.8506508084f, 0.f},
  {-0.5257311121f, -0.8506508084f, 0.f},
  {0.8506508084f, 0.f, 0.5257311121f},
  {0.8506508084f, 0.f, -0.5257311121f},
  {-0.8506508084f, 0.f, 0.5257311121f},
  {-0.8506508084f, 0.f, -0.5257311121f}};
__device__ __constant__ int c_C2V[6][2] = {{0,1},{6,7},{2,11},{4,9},{5,8},{3,10}};

// ---------- helpers ----------
__device__ inline unsigned short f2bf(float f) {
  unsigned int u = __float_as_uint(f);
  unsigned int r = (u + 0x7fffu + ((u >> 16) & 1u)) >> 16;   // RNE
  return (unsigned short)r;
}
__device__ inline float bf2f(unsigned short h) {
  return __uint_as_float(((unsigned int)h) << 16);
}

__device__ inline float sym13(const float* __restrict__ w, int k, int j) {
  if (k == 0)  return w[j == 0 ? 0 : 1];
  if (k == 1)  return w[j == 0 ? 2 : 3];
  if (k == 12) return w[j == 0 ? 4 : 5];
  int a = (k - 2) / 5, rr = (k - 2) % 5;
  return w[6 + a * 6 + c_ROLL[rr][j]];
}

// ---------- k0: weight expansion (all bf16) + fmT (bf16) + passthrough ----------
__global__ __launch_bounds__(256) void k0_expand(
    const float* __restrict__ W, const float* __restrict__ Wdir,
    const float* __restrict__ fm,
    unsigned short* __restrict__ A_bf,    // [1152][192] bf16, scaled by 0.5
    unsigned short* __restrict__ W2bf,    // [144][64][192] bf16
    unsigned short* __restrict__ Wcbf,    // [12][64][192] bf16
    unsigned short* __restrict__ fmTbf,   // [V][192] bf16
    float* __restrict__ out_fm, int V) {
  int idx = blockIdx.x * 256 + threadIdx.x;
  if (idx < 221184) {
    int row = idx / 192, ci = idx % 192;
    int h = row / 144, k = (row / 12) % 12, r = row % 12;
    int c = ci / 6, i = ci % 6;
    A_bf[idx] = f2bf(0.5f * sym13(&Wdir[(h * 32 + c) * 18], k, c_INV[r][i]));
  } else if (idx < 1990656) {
    int e = idx - 221184;
    int kr = e / 12288, rem = e % 12288;
    int k = kr / 12, r = kr % 12, d = rem / 192, ci = rem % 192;
    int c = ci / 6, i = ci % 6;
    W2bf[e] = f2bf(sym13(&W[(d * 32 + c) * 18], k, c_INV[r][i]));
  } else if (idx < 2138112) {
    int e = idx - 1990656;
    int r = e / 12288, rem = e % 12288, d = rem / 192, ci = rem % 192;
    int c = ci / 6, i = ci % 6;
    Wcbf[e] = f2bf(sym13(&W[(d * 32 + c) * 18], 12, c_INV[r][i]));
  } else {
    int e = idx - 2138112;
    if (e < 192 * V) {
      int p = e / 192, ci = e % 192, c = ci / 6, i = ci % 6;
      float v = fm[(c * V + p) * 6 + i];
      fmTbf[e] = f2bf(v);
      out_fm[(c * V + p) * 6 + i] = v;
    }
  }
}

// ---------- k1: directions + de6 + W_dim -> cross_bf [p][n][ci] bf16 ----------
__global__ __launch_bounds__(256) void k1_cross(
    const int* __restrict__ nbi, const float* __restrict__ verts,
    const float* __restrict__ fm, const float* __restrict__ Wdim,
    unsigned short* __restrict__ cross_bf, int V) {
  __shared__ float in_s[NN * 33 * 6];
  __shared__ float wd_s[33 * 32];
  __shared__ int nb_s[NN];
  int p = blockIdx.x, t = threadIdx.x;
  if (t < NN) nb_s[t] = nbi[p * NN + t];
  for (int idx = t; idx < 1056; idx += 256) wd_s[idx] = Wdim[idx];
  __syncthreads();
  for (int idx = t; idx < NN * 32 * 6; idx += 256) {
    int n = idx / 192, rest = idx % 192, c = rest / 6, i = rest % 6;
    in_s[(n * 33 + c) * 6 + i] = fm[(c * V + nb_s[n]) * 6 + i];
  }
  if (t < NN) {
    int n = t, nb = nb_s[n];
    float px = verts[p * 3 + 0], py = verts[p * 3 + 1], pz = verts[p * 3 + 2];
    float dx = verts[nb * 3 + 0] - px, dy = verts[nb * 3 + 1] - py, dz = verts[nb * 3 + 2] - pz;
    float L = sqrtf(dx * dx + dy * dy + dz * dz);
    float inv = 1.0f / fmaxf(L, 1e-12f);
    dx *= inv; dy *= inv; dz *= inv;
    float de[12];
    #pragma unroll
    for (int v = 0; v < 12; ++v)
      de[v] = c_VS[v][0] * dx + c_VS[v][1] * dy + c_VS[v][2] * dz;
    #pragma unroll
    for (int j = 0; j < 6; ++j)
      in_s[(n * 33 + 32) * 6 + j] = fmaxf(de[c_C2V[j][0]], de[c_C2V[j][1]]);
  }
  __syncthreads();
  unsigned int* dst = (unsigned int*)(cross_bf + (size_t)p * 3072);
  for (int idx = t; idx < 1536; idx += 256) {
    int n = idx / 96, cp2 = idx % 96;
    int ci0 = cp2 * 2, ci1 = ci0 + 1;
    int o0 = ci0 / 6, i0 = ci0 % 6;
    int o1 = ci1 / 6, i1 = ci1 % 6;
    float s0 = 0.f, s1 = 0.f;
    #pragma unroll
    for (int c = 0; c <= 32; ++c) {
      float f0 = in_s[(n * 33 + c) * 6 + i0];
      float f1 = in_s[(n * 33 + c) * 6 + i1];
      s0 = fmaf(wd_s[c * 32 + o0], f0, s0);
      s1 = fmaf(wd_s[c * 32 + o1], f1, s1);
    }
    dst[idx] = (unsigned int)f2bf(s0) | ((unsigned int)f2bf(s1) << 16);
  }
}

// ---------- k2: MFMA act GEMM + in-register softmax + nfm ----------
__global__ __launch_bounds__(256) void k2_main(
    const unsigned short* __restrict__ A_bf,
    const unsigned short* __restrict__ cross_bf,
    unsigned short* __restrict__ nfm, int V) {
  __shared__ unsigned short B_lds[4][16][200];  // [p][n][ci], +8 pad
  __shared__ float act_s[4][4][16][17];         // [wave][p][row][n]
  int t = threadIdx.x;
  int w = t >> 6, lane = t & 63;
  int quad = lane >> 4, col = lane & 15;
  int p0 = blockIdx.x * 4;

  for (int i = t; i < 1536; i += 256) {
    int e = i * 8;
    int p = e / 3072, off = e % 3072;
    int n = off / 192, ci = off % 192;
    *(uint4*)&B_lds[p][n][ci] =
        *(const uint4*)(cross_bf + (size_t)(p0 + p) * 3072 + off);
  }
  __syncthreads();

  int pl = quad, rl = col;

  for (int rt = w; rt < 72; rt += 4) {
    int R0 = rt * 16;
    int h = rt / 9;
    int krbase = R0 - h * 144;
    f32x4 acc[4];
    #pragma unroll
    for (int p = 0; p < 4; ++p) acc[p] = (f32x4){0.f, 0.f, 0.f, 0.f};
    const unsigned short* Abase = A_bf + (size_t)(R0 + col) * 192 + quad * 8;
    #pragma unroll
    for (int ks = 0; ks < 6; ++ks) {
      bf16x8 af = *(const bf16x8*)(Abase + ks * 32);
      #pragma unroll
      for (int p = 0; p < 4; ++p) {
        bf16x8 bfr = *(const bf16x8*)&B_lds[p][col][ks * 32 + quad * 8];
        acc[p] = __builtin_amdgcn_mfma_f32_16x16x32_bf16(af, bfr, acc[p], 0, 0, 0);
      }
    }
    #pragma unroll
    for (int p = 0; p < 4; ++p) {
      #pragma unroll
      for (int r = 0; r < 4; ++r) {
        float v = acc[p][r];
        float m = v;
        #pragma unroll
        for (int mk = 8; mk; mk >>= 1) m = fmaxf(m, __shfl_xor(m, mk, 16));
        float e = __expf(v - m);
        float s = e;
        #pragma unroll
        for (int mk = 8; mk; mk >>= 1) s += __shfl_xor(s, mk, 16);
        acc[p][r] = e / s;
      }
    }
    #pragma unroll
    for (int p = 0; p < 4; ++p)
      #pragma unroll
      for (int r = 0; r < 4; ++r)
        act_s[w][p][quad * 4 + r][col] = acc[p][r];
    __syncthreads();
    float av[16];
    #pragma unroll
    for (int n = 0; n < 16; ++n) av[n] = act_s[w][pl][rl][n];
    float o[24];
    #pragma unroll
    for (int c = 0; c < 24; ++c) o[c] = 0.f;
    int h24 = h * 24;
    #pragma unroll
    for (int n = 0; n < 16; ++n) {
      float a = av[n];
      const uint4* cp = (const uint4*)&B_lds[pl][n][h24];
      uint4 u0 = cp[0], u1 = cp[1], u2 = cp[2];
      unsigned int uu[12] = {u0.x, u0.y, u0.z, u0.w, u1.x, u1.y, u1.z, u1.w,
                             u2.x, u2.y, u2.z, u2.w};
      #pragma unroll
      for (int q = 0; q < 12; ++q) {
        o[2 * q]     = fmaf(a, __uint_as_float(uu[q] << 16), o[2 * q]);
        o[2 * q + 1] = fmaf(a, __uint_as_float(uu[q] & 0xffff0000u), o[2 * q + 1]);
      }
    }
    unsigned int pk[12];
    #pragma unroll
    for (int q = 0; q < 12; ++q)
      pk[q] = (unsigned int)f2bf(o[2 * q]) | ((unsigned int)f2bf(o[2 * q + 1]) << 16);
    size_t ob = ((size_t)(p0 + pl) * 144 + (size_t)(krbase + rl)) * 192 + h24;
    uint4* dst = (uint4*)(nfm + ob);
    dst[0] = make_uint4(pk[0], pk[1], pk[2], pk[3]);
    dst[1] = make_uint4(pk[4], pk[5], pk[6], pk[7]);
    dst[2] = make_uint4(pk[8], pk[9], pk[10], pk[11]);
    __syncthreads();
  }
}

// ---------- k3: MFMA feat GEMMs + center -> ka12[r][d][p] ----------
// one wave per block; grid (V/32, 12) = 768 blocks -> even 3 blocks/CU.
// No LDS, no barriers: fragments straight from global (A is L2-resident).
__global__ __launch_bounds__(64) void k3_feat(
    const unsigned short* __restrict__ W2bf,
    const unsigned short* __restrict__ Wcbf,
    const unsigned short* __restrict__ fmTbf,
    const unsigned short* __restrict__ nfm,
    float* __restrict__ ka12, int V) {
  int pb = blockIdx.x, r = blockIdx.y;
  int lane = threadIdx.x;
  int quad = lane >> 4, col = lane & 15;
  int p0 = pb * 32;
  f32x4 acc[4][2];
  #pragma unroll
  for (int m = 0; m < 4; ++m)
    #pragma unroll
    for (int j = 0; j < 2; ++j) acc[m][j] = (f32x4){0.f, 0.f, 0.f, 0.f};

  const unsigned short* Bn0 = nfm + (size_t)(p0 + col) * 27648;
  const unsigned short* Bn1 = nfm + (size_t)(p0 + 16 + col) * 27648;
  const unsigned short* Bc0 = fmTbf + (size_t)(p0 + col) * 192;
  const unsigned short* Bc1 = fmTbf + (size_t)(p0 + 16 + col) * 192;

  for (int kb = 0; kb < 13; ++kb) {
    const unsigned short *Ab, *Bb0, *Bb1;
    if (kb < 12) {
      int kr = kb * 12 + r;
      Ab = W2bf + (size_t)kr * (64 * 192);
      Bb0 = Bn0 + (size_t)kr * 192;
      Bb1 = Bn1 + (size_t)kr * 192;
    } else {
      Ab = Wcbf + (size_t)r * (64 * 192);
      Bb0 = Bc0; Bb1 = Bc1;
    }
    #pragma unroll
    for (int ks = 0; ks < 6; ++ks) {
      int ko = ks * 32 + quad * 8;
      bf16x8 b0 = *(const bf16x8*)(Bb0 + ko);
      bf16x8 b1 = *(const bf16x8*)(Bb1 + ko);
      #pragma unroll
      for (int m = 0; m < 4; ++m) {
        bf16x8 a = *(const bf16x8*)(Ab + (size_t)(m * 16 + col) * 192 + ko);
        acc[m][0] = __builtin_amdgcn_mfma_f32_16x16x32_bf16(a, b0, acc[m][0], 0, 0, 0);
        acc[m][1] = __builtin_amdgcn_mfma_f32_16x16x32_bf16(a, b1, acc[m][1], 0, 0, 0);
      }
    }
  }
  #pragma unroll
  for (int m = 0; m < 4; ++m) {
    #pragma unroll
    for (int rr = 0; rr < 4; ++rr) {
      int d = m * 16 + quad * 4 + rr;
      float* dst = &ka12[(size_t)(r * 64 + d) * V + p0 + col];
      dst[0]  = acc[m][0][rr];
      dst[16] = acc[m][1][rr];
    }
  }
}

// ---------- k4: c2v max -> ka output ----------
__global__ __launch_bounds__(256) void k4_final(
    const float* __restrict__ ka12, float* __restrict__ out, int V) {
  int idx = blockIdx.x * 256 + threadIdx.x;
  int total = DO * V * 6;
  if (idx >= total) return;
  int j = idx % 6, rem = idx / 6;
  int p = rem % V, d = rem / V;
  size_t base = (size_t)d * V + p;
  float a = ka12[(size_t)c_C2V[j][0] * 64 * V + base];
  float b = ka12[(size_t)c_C2V[j][1] * 64 * V + base];
  out[idx] = fmaxf(a, b);
}

// ---------- host ----------
extern "C" void kernel_launch(void* const* d_in, const int* in_sizes, int n_in,
                              void* d_out, int out_size, void* d_ws, size_t ws_size,
                              hipStream_t stream) {
  const int* nbi = (const int*)d_in[0];
  const float* verts = (const float*)d_in[1];
  const float* fm = (const float*)d_in[2];
  const float* Wdim = (const float*)d_in[3];
  const float* W = (const float*)d_in[4];
  const float* Wdir = (const float*)d_in[5];
  float* out = (float*)d_out;
  float* ws = (float*)d_ws;
  int V = in_sizes[0] / NN;   // 2048

  unsigned short* A_bf  = (unsigned short*)ws;             // 221184 ush
  unsigned short* W2bf  = (unsigned short*)(ws + 110592);  // 1769472 ush
  unsigned short* Wcbf  = (unsigned short*)(ws + 995328);  // 147456 ush
  unsigned short* fmTbf = (unsigned short*)(ws + 1069056); // 192*V ush
  size_t o = 1069056 + (size_t)96 * V;
  unsigned short* cross_bf = (unsigned short*)(ws + o);    // 3072*V ush
  o += (size_t)1536 * V;
  float* ka12 = ws + o;                                    // 768*V f32
  o += (size_t)768 * V;
  unsigned short* nfm = (unsigned short*)(ws + o);         // 27648*V ush

  int n0 = 2138112 + 192 * V;
  k0_expand<<<(n0 + 255) / 256, 256, 0, stream>>>(W, Wdir, fm, A_bf, W2bf, Wcbf, fmTbf,
                                                  out + (size_t)DO * V * 6, V);
  k1_cross<<<V, 256, 0, stream>>>(nbi, verts, fm, Wdim, cross_bf, V);
  k2_main<<<V / 4, 256, 0, stream>>>(A_bf, cross_bf, nfm, V);
  k3_feat<<<dim3(V / 32, 12), 64, 0, stream>>>(W2bf, Wcbf, fmTbf, nfm, ka12, V);
  k4_final<<<(DO * V * 6 + 255) / 256, 256, 0, stream>>>(ka12, out, V);
}

// Round 4
// 294.697 us; speedup vs baseline: 3.2185x; 1.1457x over previous
//
#include <hip/hip_runtime.h>
#include <cstdint>
#include <cstddef>

#define NN 16   // neighbors
#define DI 32
#define DO 64

typedef short bf16x8 __attribute__((ext_vector_type(8)));
typedef float f32x4 __attribute__((ext_vector_type(4)));

// ---------- tables ----------
__device__ __constant__ int c_INV[12][6] = {
  {0,1,2,3,4,5},{0,5,4,3,2,1},{4,3,0,5,2,1},{1,2,4,3,5,0},
  {3,5,2,0,4,1},{1,4,3,5,0,2},{4,0,3,1,2,5},{1,0,2,4,3,5},
  {4,1,2,5,0,3},{3,1,4,0,2,5},{2,1,4,5,3,0},{4,5,0,3,1,2}};
__device__ __constant__ int c_ROLL[5][6] = {
  {0,1,2,3,4,5},{0,2,3,4,5,1},{0,3,4,5,1,2},{0,4,5,1,2,3},{0,5,1,2,3,4}};
__device__ __constant__ float c_VS[12][3] = {
  {0.f, 0.5257311121f, 0.8506508084f},
  {0.f, 0.5257311121f, -0.8506508084f},
  {0.f, -0.5257311121f, 0.8506508084f},
  {0.f, -0.5257311121f, -0.8506508084f},
  {0.5257311121f, 0.8506508084f, 0.f},
  {0.5257311121f, -0.8506508084f, 0.f},
  {-0.5257311121f, 0.8506508084f, 0.f},
  {-0.5257311121f, -0.8506508084f, 0.f},
  {0.8506508084f, 0.f, 0.5257311121f},
  {0.8506508084f, 0.f, -0.5257311121f},
  {-0.8506508084f, 0.f, 0.5257311121f},
  {-0.8506508084f, 0.f, -0.5257311121f}};
__device__ __constant__ int c_C2V[6][2] = {{0,1},{6,7},{2,11},{4,9},{5,8},{3,10}};

// ---------- helpers ----------
__device__ inline unsigned short f2bf(float f) {
  unsigned int u = __float_as_uint(f);
  unsigned int r = (u + 0x7fffu + ((u >> 16) & 1u)) >> 16;   // RNE
  return (unsigned short)r;
}
__device__ inline float bf2f(unsigned short h) {
  return __uint_as_float(((unsigned int)h) << 16);
}

__device__ inline float sym13(const float* __restrict__ w, int k, int j) {
  if (k == 0)  return w[j == 0 ? 0 : 1];
  if (k == 1)  return w[j == 0 ? 2 : 3];
  if (k == 12) return w[j == 0 ? 4 : 5];
  int a = (k - 2) / 5, rr = (k - 2) % 5;
  return w[6 + a * 6 + c_ROLL[rr][j]];
}

// ---------- k0: weight expansion (all bf16) + fmT (bf16) + passthrough ----------
__global__ __launch_bounds__(256) void k0_expand(
    const float* __restrict__ W, const float* __restrict__ Wdir,
    const float* __restrict__ fm,
    unsigned short* __restrict__ A_bf,    // [1152][192] bf16, scaled by 0.5
    unsigned short* __restrict__ W2bf,    // [144][64][192] bf16
    unsigned short* __restrict__ Wcbf,    // [12][64][192] bf16
    unsigned short* __restrict__ fmTbf,   // [V][192] bf16
    float* __restrict__ out_fm, int V) {
  int idx = blockIdx.x * 256 + threadIdx.x;
  if (idx < 221184) {
    int row = idx / 192, ci = idx % 192;
    int h = row / 144, k = (row / 12) % 12, r = row % 12;
    int c = ci / 6, i = ci % 6;
    A_bf[idx] = f2bf(0.5f * sym13(&Wdir[(h * 32 + c) * 18], k, c_INV[r][i]));
  } else if (idx < 1990656) {
    int e = idx - 221184;
    int kr = e / 12288, rem = e % 12288;
    int k = kr / 12, r = kr % 12, d = rem / 192, ci = rem % 192;
    int c = ci / 6, i = ci % 6;
    W2bf[e] = f2bf(sym13(&W[(d * 32 + c) * 18], k, c_INV[r][i]));
  } else if (idx < 2138112) {
    int e = idx - 1990656;
    int r = e / 12288, rem = e % 12288, d = rem / 192, ci = rem % 192;
    int c = ci / 6, i = ci % 6;
    Wcbf[e] = f2bf(sym13(&W[(d * 32 + c) * 18], 12, c_INV[r][i]));
  } else {
    int e = idx - 2138112;
    if (e < 192 * V) {
      int p = e / 192, ci = e % 192, c = ci / 6, i = ci % 6;
      float v = fm[(c * V + p) * 6 + i];
      fmTbf[e] = f2bf(v);
      out_fm[(c * V + p) * 6 + i] = v;
    }
  }
}

// ---------- k1: directions + de6 + W_dim -> cross_bf [p][n][ci] bf16 ----------
__global__ __launch_bounds__(256) void k1_cross(
    const int* __restrict__ nbi, const float* __restrict__ verts,
    const float* __restrict__ fm, const float* __restrict__ Wdim,
    unsigned short* __restrict__ cross_bf, int V) {
  __shared__ float in_s[NN * 33 * 6];
  __shared__ float wd_s[33 * 32];
  __shared__ int nb_s[NN];
  int p = blockIdx.x, t = threadIdx.x;
  if (t < NN) nb_s[t] = nbi[p * NN + t];
  for (int idx = t; idx < 1056; idx += 256) wd_s[idx] = Wdim[idx];
  __syncthreads();
  for (int idx = t; idx < NN * 32 * 6; idx += 256) {
    int n = idx / 192, rest = idx % 192, c = rest / 6, i = rest % 6;
    in_s[(n * 33 + c) * 6 + i] = fm[(c * V + nb_s[n]) * 6 + i];
  }
  if (t < NN) {
    int n = t, nb = nb_s[n];
    float px = verts[p * 3 + 0], py = verts[p * 3 + 1], pz = verts[p * 3 + 2];
    float dx = verts[nb * 3 + 0] - px, dy = verts[nb * 3 + 1] - py, dz = verts[nb * 3 + 2] - pz;
    float L = sqrtf(dx * dx + dy * dy + dz * dz);
    float inv = 1.0f / fmaxf(L, 1e-12f);
    dx *= inv; dy *= inv; dz *= inv;
    float de[12];
    #pragma unroll
    for (int v = 0; v < 12; ++v)
      de[v] = c_VS[v][0] * dx + c_VS[v][1] * dy + c_VS[v][2] * dz;
    #pragma unroll
    for (int j = 0; j < 6; ++j)
      in_s[(n * 33 + 32) * 6 + j] = fmaxf(de[c_C2V[j][0]], de[c_C2V[j][1]]);
  }
  __syncthreads();
  unsigned int* dst = (unsigned int*)(cross_bf + (size_t)p * 3072);
  for (int idx = t; idx < 1536; idx += 256) {
    int n = idx / 96, cp2 = idx % 96;
    int ci0 = cp2 * 2, ci1 = ci0 + 1;
    int o0 = ci0 / 6, i0 = ci0 % 6;
    int o1 = ci1 / 6, i1 = ci1 % 6;
    float s0 = 0.f, s1 = 0.f;
    #pragma unroll
    for (int c = 0; c <= 32; ++c) {
      float f0 = in_s[(n * 33 + c) * 6 + i0];
      float f1 = in_s[(n * 33 + c) * 6 + i1];
      s0 = fmaf(wd_s[c * 32 + o0], f0, s0);
      s1 = fmaf(wd_s[c * 32 + o1], f1, s1);
    }
    dst[idx] = (unsigned int)f2bf(s0) | ((unsigned int)f2bf(s1) << 16);
  }
}

// ---------- k2: MFMA act GEMM + in-register softmax + MFMA nfm ----------
// 2 vertices/block, 4 waves, barrier-free tile loop. LDS 44032 B -> 3 blocks/CU.
// nfm layout: [p][h(8)][kr(144)][24] bf16 (h-slice contiguous -> 768B write runs)
__global__ __launch_bounds__(256) void k2_main(
    const unsigned short* __restrict__ A_bf,
    const unsigned short* __restrict__ cross_bf,
    unsigned short* __restrict__ nfm, int V) {
  __shared__ __align__(16) unsigned short crossT[2][192][40];  // [p][ci][n], n in [16,32) zero
  __shared__ __align__(16) unsigned short act_bs[4][2][16][40]; // [w][p][kr][n], n in [16,32) zero
  __shared__ __align__(16) unsigned short stg[4][2][16][24];    // [w][p][kr][ci24] staging
  int t = threadIdx.x;
  int w = t >> 6, lane = t & 63;
  int quad = lane >> 4, col = lane & 15;
  int p0 = blockIdx.x * 2;

  // phase-A B-frags (cross as B operand) straight from global — tile-invariant
  bf16x8 Bfr[2][6];
  #pragma unroll
  for (int p = 0; p < 2; ++p)
    #pragma unroll
    for (int ks = 0; ks < 6; ++ks)
      Bfr[p][ks] = *(const bf16x8*)(cross_bf + (size_t)(p0 + p) * 3072 + col * 192 + ks * 32 + quad * 8);

  // build crossT[p][ci][n] (transpose) + zero pads
  for (int idx = t; idx < 3072; idx += 256) {       // uint-pair reads of cross
    int p = idx / 1536, rem = idx % 1536;
    int n = rem / 96, ci2 = rem % 96;
    unsigned int u = ((const unsigned int*)cross_bf)[(size_t)(p0 + p) * 1536 + rem];
    crossT[p][ci2 * 2][n]     = (unsigned short)(u & 0xffffu);
    crossT[p][ci2 * 2 + 1][n] = (unsigned short)(u >> 16);
  }
  for (int idx = t; idx < 6144; idx += 256) {       // zero crossT n in [16,32)
    int p = idx / 3072, rem = idx % 3072;
    int ci = rem / 16, n = 16 + rem % 16;
    crossT[p][ci][n] = 0;
  }
  for (int idx = t; idx < 2048; idx += 256) {       // zero act_bs n in [16,32)
    int ww = idx / 512, rem = idx % 512;
    int p = rem / 256, rem2 = rem % 256;
    int kr = rem2 / 16, n = 16 + rem2 % 16;
    act_bs[ww][p][kr][n] = 0;
  }
  __syncthreads();   // the only block barrier

  for (int rt = w; rt < 72; rt += 4) {
    int R0 = rt * 16;
    int h = rt / 9;
    int krbase = R0 - h * 144;
    // ---- phase A: act = A_w x cross^T ----
    f32x4 acc[2];
    acc[0] = (f32x4){0.f, 0.f, 0.f, 0.f};
    acc[1] = (f32x4){0.f, 0.f, 0.f, 0.f};
    const unsigned short* Abase = A_bf + (size_t)(R0 + col) * 192 + quad * 8;
    #pragma unroll
    for (int ks = 0; ks < 6; ++ks) {
      bf16x8 af = *(const bf16x8*)(Abase + ks * 32);
      acc[0] = __builtin_amdgcn_mfma_f32_16x16x32_bf16(af, Bfr[0][ks], acc[0], 0, 0, 0);
      acc[1] = __builtin_amdgcn_mfma_f32_16x16x32_bf16(af, Bfr[1][ks], acc[1], 0, 0, 0);
    }
    // ---- softmax over n (C layout: col = n) -> act_bs bf16 ----
    #pragma unroll
    for (int p = 0; p < 2; ++p) {
      #pragma unroll
      for (int r = 0; r < 4; ++r) {
        float v = acc[p][r];
        float m = v;
        #pragma unroll
        for (int mk = 8; mk; mk >>= 1) m = fmaxf(m, __shfl_xor(m, mk, 16));
        float e = __expf(v - m);
        float s = e;
        #pragma unroll
        for (int mk = 8; mk; mk >>= 1) s += __shfl_xor(s, mk, 16);
        act_bs[w][p][quad * 4 + r][col] = f2bf(e / s);
      }
    }
    asm volatile("s_waitcnt lgkmcnt(0)" ::: "memory");  // intra-wave LDS transpose fence
    // ---- phase B: nfm tile = act x cross (K=32, n padded with zeros) ----
    bf16x8 aa0 = *(const bf16x8*)&act_bs[w][0][col][quad * 8];
    bf16x8 aa1 = *(const bf16x8*)&act_bs[w][1][col][quad * 8];
    int row0 = h * 24 + col;
    int row1 = min(h * 24 + 16 + col, 191);
    bf16x8 b00 = *(const bf16x8*)&crossT[0][row0][quad * 8];
    bf16x8 b01 = *(const bf16x8*)&crossT[0][row1][quad * 8];
    bf16x8 b10 = *(const bf16x8*)&crossT[1][row0][quad * 8];
    bf16x8 b11 = *(const bf16x8*)&crossT[1][row1][quad * 8];
    f32x4 o00 = (f32x4){0.f,0.f,0.f,0.f}, o01 = o00, o10 = o00, o11 = o00;
    o00 = __builtin_amdgcn_mfma_f32_16x16x32_bf16(aa0, b00, o00, 0, 0, 0);
    o01 = __builtin_amdgcn_mfma_f32_16x16x32_bf16(aa0, b01, o01, 0, 0, 0);
    o10 = __builtin_amdgcn_mfma_f32_16x16x32_bf16(aa1, b10, o10, 0, 0, 0);
    o11 = __builtin_amdgcn_mfma_f32_16x16x32_bf16(aa1, b11, o11, 0, 0, 0);
    // ---- stage C tiles (col = ci, row = kr) as bf16 [p][16][24] ----
    #pragma unroll
    for (int r = 0; r < 4; ++r) {
      stg[w][0][quad * 4 + r][col] = f2bf(o00[r]);
      stg[w][1][quad * 4 + r][col] = f2bf(o10[r]);
    }
    if (col < 8) {
      #pragma unroll
      for (int r = 0; r < 4; ++r) {
        stg[w][0][quad * 4 + r][16 + col] = f2bf(o01[r]);
        stg[w][1][quad * 4 + r][16 + col] = f2bf(o11[r]);
      }
    }
    asm volatile("s_waitcnt lgkmcnt(0)" ::: "memory");
    // ---- cooperative 768B-contiguous writes ----
    if (lane < 48) {
      #pragma unroll
      for (int p = 0; p < 2; ++p) {
        uint4 v = ((const uint4*)&stg[w][p][0][0])[lane];
        uint4* gdst = (uint4*)(nfm + ((((size_t)(p0 + p) * 8 + h) * 144 + krbase) * 24));
        gdst[lane] = v;
      }
    }
  }
}

// ---------- k3: MFMA feat GEMMs + center -> ka12[r][d][p] ----------
// one wave per block; nfm layout [p][h][144][24]
__global__ __launch_bounds__(64) void k3_feat(
    const unsigned short* __restrict__ W2bf,
    const unsigned short* __restrict__ Wcbf,
    const unsigned short* __restrict__ fmTbf,
    const unsigned short* __restrict__ nfm,
    float* __restrict__ ka12, int V) {
  int pb = blockIdx.x, r = blockIdx.y;
  int lane = threadIdx.x;
  int quad = lane >> 4, col = lane & 15;
  int p0 = pb * 32;
  f32x4 acc[4][2];
  #pragma unroll
  for (int m = 0; m < 4; ++m)
    #pragma unroll
    for (int j = 0; j < 2; ++j) acc[m][j] = (f32x4){0.f, 0.f, 0.f, 0.f};

  // per-lane ci chunk -> (h, offset) bases within nfm p-row
  int base24[6];
  #pragma unroll
  for (int ks = 0; ks < 6; ++ks) {
    int ci = ks * 32 + quad * 8;
    int hh = ci / 24, oo = ci - hh * 24;
    base24[ks] = hh * 3456 + oo;   // h*144*24 + off
  }

  const unsigned short* Bn0 = nfm + (size_t)(p0 + col) * 27648;
  const unsigned short* Bn1 = nfm + (size_t)(p0 + 16 + col) * 27648;
  const unsigned short* Bc0 = fmTbf + (size_t)(p0 + col) * 192;
  const unsigned short* Bc1 = fmTbf + (size_t)(p0 + 16 + col) * 192;

  for (int kb = 0; kb < 13; ++kb) {
    const unsigned short* Ab;
    if (kb < 12) Ab = W2bf + (size_t)(kb * 12 + r) * (64 * 192);
    else         Ab = Wcbf + (size_t)r * (64 * 192);
    int kr24 = (kb * 12 + r) * 24;
    #pragma unroll
    for (int ks = 0; ks < 6; ++ks) {
      int ko = ks * 32 + quad * 8;
      bf16x8 b0, b1;
      if (kb < 12) {
        b0 = *(const bf16x8*)(Bn0 + base24[ks] + kr24);
        b1 = *(const bf16x8*)(Bn1 + base24[ks] + kr24);
      } else {
        b0 = *(const bf16x8*)(Bc0 + ko);
        b1 = *(const bf16x8*)(Bc1 + ko);
      }
      #pragma unroll
      for (int m = 0; m < 4; ++m) {
        bf16x8 a = *(const bf16x8*)(Ab + (size_t)(m * 16 + col) * 192 + ko);
        acc[m][0] = __builtin_amdgcn_mfma_f32_16x16x32_bf16(a, b0, acc[m][0], 0, 0, 0);
        acc[m][1] = __builtin_amdgcn_mfma_f32_16x16x32_bf16(a, b1, acc[m][1], 0, 0, 0);
      }
    }
  }
  #pragma unroll
  for (int m = 0; m < 4; ++m) {
    #pragma unroll
    for (int rr = 0; rr < 4; ++rr) {
      int d = m * 16 + quad * 4 + rr;
      float* dst = &ka12[(size_t)(r * 64 + d) * V + p0 + col];
      dst[0]  = acc[m][0][rr];
      dst[16] = acc[m][1][rr];
    }
  }
}

// ---------- k4: c2v max -> ka output ----------
__global__ __launch_bounds__(256) void k4_final(
    const float* __restrict__ ka12, float* __restrict__ out, int V) {
  int idx = blockIdx.x * 256 + threadIdx.x;
  int total = DO * V * 6;
  if (idx >= total) return;
  int j = idx % 6, rem = idx / 6;
  int p = rem % V, d = rem / V;
  size_t base = (size_t)d * V + p;
  float a = ka12[(size_t)c_C2V[j][0] * 64 * V + base];
  float b = ka12[(size_t)c_C2V[j][1] * 64 * V + base];
  out[idx] = fmaxf(a, b);
}

// ---------- host ----------
extern "C" void kernel_launch(void* const* d_in, const int* in_sizes, int n_in,
                              void* d_out, int out_size, void* d_ws, size_t ws_size,
                              hipStream_t stream) {
  const int* nbi = (const int*)d_in[0];
  const float* verts = (const float*)d_in[1];
  const float* fm = (const float*)d_in[2];
  const float* Wdim = (const float*)d_in[3];
  const float* W = (const float*)d_in[4];
  const float* Wdir = (const float*)d_in[5];
  float* out = (float*)d_out;
  float* ws = (float*)d_ws;
  int V = in_sizes[0] / NN;   // 2048

  unsigned short* A_bf  = (unsigned short*)ws;             // 221184 ush
  unsigned short* W2bf  = (unsigned short*)(ws + 110592);  // 1769472 ush
  unsigned short* Wcbf  = (unsigned short*)(ws + 995328);  // 147456 ush
  unsigned short* fmTbf = (unsigned short*)(ws + 1069056); // 192*V ush
  size_t o = 1069056 + (size_t)96 * V;
  unsigned short* cross_bf = (unsigned short*)(ws + o);    // 3072*V ush
  o += (size_t)1536 * V;
  float* ka12 = ws + o;                                    // 768*V f32
  o += (size_t)768 * V;
  unsigned short* nfm = (unsigned short*)(ws + o);         // 27648*V ush  [p][h][144][24]

  int n0 = 2138112 + 192 * V;
  k0_expand<<<(n0 + 255) / 256, 256, 0, stream>>>(W, Wdir, fm, A_bf, W2bf, Wcbf, fmTbf,
                                                  out + (size_t)DO * V * 6, V);
  k1_cross<<<V, 256, 0, stream>>>(nbi, verts, fm, Wdim, cross_bf, V);
  k2_main<<<V / 2, 256, 0, stream>>>(A_bf, cross_bf, nfm, V);
  k3_feat<<<dim3(V / 32, 12), 64, 0, stream>>>(W2bf, Wcbf, fmTbf, nfm, ka12, V);
  k4_final<<<(DO * V * 6 + 255) / 256, 256, 0, stream>>>(ka12, out, V);
}

// Round 5
// 265.808 us; speedup vs baseline: 3.5682x; 1.1087x over previous
//
#include <hip/hip_runtime.h>
#include <cstdint>
#include <cstddef>

#define NN 16   // neighbors
#define DI 32
#define DO 64

typedef short bf16x8 __attribute__((ext_vector_type(8)));
typedef float f32x4 __attribute__((ext_vector_type(4)));

// ---------- tables ----------
__device__ __constant__ int c_INV[12][6] = {
  {0,1,2,3,4,5},{0,5,4,3,2,1},{4,3,0,5,2,1},{1,2,4,3,5,0},
  {3,5,2,0,4,1},{1,4,3,5,0,2},{4,0,3,1,2,5},{1,0,2,4,3,5},
  {4,1,2,5,0,3},{3,1,4,0,2,5},{2,1,4,5,3,0},{4,5,0,3,1,2}};
__device__ __constant__ int c_ROLL[5][6] = {
  {0,1,2,3,4,5},{0,2,3,4,5,1},{0,3,4,5,1,2},{0,4,5,1,2,3},{0,5,1,2,3,4}};
__device__ __constant__ float c_VS[12][3] = {
  {0.f, 0.5257311121f, 0.8506508084f},
  {0.f, 0.5257311121f, -0.8506508084f},
  {0.f, -0.5257311121f, 0.8506508084f},
  {0.f, -0.5257311121f, -0.8506508084f},
  {0.5257311121f, 0.8506508084f, 0.f},
  {0.5257311121f, -0.8506508084f, 0.f},
  {-0.5257311121f, 0.8506508084f, 0.f},
  {-0.5257311121f, -0.8506508084f, 0.f},
  {0.8506508084f, 0.f, 0.5257311121f},
  {0.8506508084f, 0.f, -0.5257311121f},
  {-0.8506508084f, 0.f, 0.5257311121f},
  {-0.8506508084f, 0.f, -0.5257311121f}};
__device__ __constant__ int c_C2V[6][2] = {{0,1},{6,7},{2,11},{4,9},{5,8},{3,10}};

// ---------- helpers ----------
__device__ inline unsigned short f2bf(float f) {
  unsigned int u = __float_as_uint(f);
  unsigned int r = (u + 0x7fffu + ((u >> 16) & 1u)) >> 16;   // RNE
  return (unsigned short)r;
}
__device__ inline float bf2f(unsigned short h) {
  return __uint_as_float(((unsigned int)h) << 16);
}
__device__ inline unsigned int pack2(float a, float b) {
  return (unsigned int)f2bf(a) | ((unsigned int)f2bf(b) << 16);
}

__device__ inline float sym13(const float* __restrict__ w, int k, int j) {
  if (k == 0)  return w[j == 0 ? 0 : 1];
  if (k == 1)  return w[j == 0 ? 2 : 3];
  if (k == 12) return w[j == 0 ? 4 : 5];
  int a = (k - 2) / 5, rr = (k - 2) % 5;
  return w[6 + a * 6 + c_ROLL[rr][j]];
}

// ---------- k0: weight expansion (all bf16) + fmT (bf16) + passthrough ----------
__global__ __launch_bounds__(256) void k0_expand(
    const float* __restrict__ W, const float* __restrict__ Wdir,
    const float* __restrict__ fm,
    unsigned short* __restrict__ A_bf,    // [1152][192] bf16, scaled by 0.5
    unsigned short* __restrict__ W2bf,    // [144][64][192] bf16
    unsigned short* __restrict__ Wcbf,    // [12][64][192] bf16
    unsigned short* __restrict__ fmTbf,   // [V][192] bf16
    float* __restrict__ out_fm, int V) {
  int idx = blockIdx.x * 256 + threadIdx.x;
  if (idx < 221184) {
    int row = idx / 192, ci = idx % 192;
    int h = row / 144, k = (row / 12) % 12, r = row % 12;
    int c = ci / 6, i = ci % 6;
    A_bf[idx] = f2bf(0.5f * sym13(&Wdir[(h * 32 + c) * 18], k, c_INV[r][i]));
  } else if (idx < 1990656) {
    int e = idx - 221184;
    int kr = e / 12288, rem = e % 12288;
    int k = kr / 12, r = kr % 12, d = rem / 192, ci = rem % 192;
    int c = ci / 6, i = ci % 6;
    W2bf[e] = f2bf(sym13(&W[(d * 32 + c) * 18], k, c_INV[r][i]));
  } else if (idx < 2138112) {
    int e = idx - 1990656;
    int r = e / 12288, rem = e % 12288, d = rem / 192, ci = rem % 192;
    int c = ci / 6, i = ci % 6;
    Wcbf[e] = f2bf(sym13(&W[(d * 32 + c) * 18], 12, c_INV[r][i]));
  } else {
    int e = idx - 2138112;
    if (e < 192 * V) {
      int p = e / 192, ci = e % 192, c = ci / 6, i = ci % 6;
      float v = fm[(c * V + p) * 6 + i];
      fmTbf[e] = f2bf(v);
      out_fm[(c * V + p) * 6 + i] = v;
    }
  }
}

// ---------- k1: directions + de6 + W_dim -> cross_bf [p][n][ci] bf16 ----------
__global__ __launch_bounds__(256) void k1_cross(
    const int* __restrict__ nbi, const float* __restrict__ verts,
    const float* __restrict__ fm, const float* __restrict__ Wdim,
    unsigned short* __restrict__ cross_bf, int V) {
  __shared__ float in_s[NN * 33 * 6];
  __shared__ float wd_s[33 * 32];
  __shared__ int nb_s[NN];
  int p = blockIdx.x, t = threadIdx.x;
  if (t < NN) nb_s[t] = nbi[p * NN + t];
  for (int idx = t; idx < 1056; idx += 256) wd_s[idx] = Wdim[idx];
  __syncthreads();
  for (int idx = t; idx < NN * 32 * 6; idx += 256) {
    int n = idx / 192, rest = idx % 192, c = rest / 6, i = rest % 6;
    in_s[(n * 33 + c) * 6 + i] = fm[(c * V + nb_s[n]) * 6 + i];
  }
  if (t < NN) {
    int n = t, nb = nb_s[n];
    float px = verts[p * 3 + 0], py = verts[p * 3 + 1], pz = verts[p * 3 + 2];
    float dx = verts[nb * 3 + 0] - px, dy = verts[nb * 3 + 1] - py, dz = verts[nb * 3 + 2] - pz;
    float L = sqrtf(dx * dx + dy * dy + dz * dz);
    float inv = 1.0f / fmaxf(L, 1e-12f);
    dx *= inv; dy *= inv; dz *= inv;
    float de[12];
    #pragma unroll
    for (int v = 0; v < 12; ++v)
      de[v] = c_VS[v][0] * dx + c_VS[v][1] * dy + c_VS[v][2] * dz;
    #pragma unroll
    for (int j = 0; j < 6; ++j)
      in_s[(n * 33 + 32) * 6 + j] = fmaxf(de[c_C2V[j][0]], de[c_C2V[j][1]]);
  }
  __syncthreads();
  unsigned int* dst = (unsigned int*)(cross_bf + (size_t)p * 3072);
  for (int idx = t; idx < 1536; idx += 256) {
    int n = idx / 96, cp2 = idx % 96;
    int ci0 = cp2 * 2, ci1 = ci0 + 1;
    int o0 = ci0 / 6, i0 = ci0 % 6;
    int o1 = ci1 / 6, i1 = ci1 % 6;
    float s0 = 0.f, s1 = 0.f;
    #pragma unroll
    for (int c = 0; c <= 32; ++c) {
      float f0 = in_s[(n * 33 + c) * 6 + i0];
      float f1 = in_s[(n * 33 + c) * 6 + i1];
      s0 = fmaf(wd_s[c * 32 + o0], f0, s0);
      s1 = fmaf(wd_s[c * 32 + o1], f1, s1);
    }
    dst[idx] = (unsigned int)f2bf(s0) | ((unsigned int)f2bf(s1) << 16);
  }
}

// ---------- k2: MFMA act GEMM (operand-swapped) + row-softmax + MFMA nfm ----------
// 2 vertices/block, 4 waves, barrier-free tile loop. LDS 47104 B -> 3 blocks/CU.
// Phase A: D[m=n][nn=kr] (A-op = cross frag, B-op = weight frag) so softmax over n
// is 3 in-lane ops + 2 shfl_xor (16/32) instead of 4 dependent width-16 swizzles.
// Phase B: D[m=ci][nn=kr] so each lane stages 4 consecutive ci as packed uint2.
// nfm layout: [p][h(8)][kr(144)][24] bf16 (768B contiguous write runs)
__global__ __launch_bounds__(256) void k2_main(
    const unsigned short* __restrict__ A_bf,
    const unsigned short* __restrict__ cross_bf,
    unsigned short* __restrict__ nfm, int V) {
  __shared__ __align__(16) unsigned short crossT[2][192][40];   // [p][ci][n], n in [16,32) zero
  __shared__ __align__(16) unsigned short act_bs[4][2][16][40]; // [w][p][kr][n], n in [16,32) zero
  __shared__ __align__(16) unsigned short stg[4][2][16][24];    // [w][p][kr][ci24] staging
  int t = threadIdx.x;
  int w = t >> 6, lane = t & 63;
  int quad = lane >> 4, col = lane & 15;
  int p0 = blockIdx.x * 2;

  // phase-A A-operand frags (cross, m=n): tile-invariant, straight from global
  bf16x8 Afr[2][6];
  #pragma unroll
  for (int p = 0; p < 2; ++p)
    #pragma unroll
    for (int ks = 0; ks < 6; ++ks)
      Afr[p][ks] = *(const bf16x8*)(cross_bf + (size_t)(p0 + p) * 3072 + col * 192 + ks * 32 + quad * 8);

  // build crossT[p][ci][n] (transpose) + zero pads
  for (int idx = t; idx < 3072; idx += 256) {
    int p = idx / 1536, rem = idx % 1536;
    int n = rem / 96, ci2 = rem % 96;
    unsigned int u = ((const unsigned int*)cross_bf)[(size_t)(p0 + p) * 1536 + rem];
    crossT[p][ci2 * 2][n]     = (unsigned short)(u & 0xffffu);
    crossT[p][ci2 * 2 + 1][n] = (unsigned short)(u >> 16);
  }
  for (int idx = t; idx < 6144; idx += 256) {       // zero crossT n in [16,32)
    int p = idx / 3072, rem = idx % 3072;
    int ci = rem / 16, n = 16 + rem % 16;
    crossT[p][ci][n] = 0;
  }
  for (int idx = t; idx < 2048; idx += 256) {       // zero act_bs n in [16,32)
    int ww = idx / 512, rem = idx % 512;
    int p = rem / 256, rem2 = rem % 256;
    int kr = rem2 / 16, n = 16 + rem2 % 16;
    act_bs[ww][p][kr][n] = 0;
  }
  __syncthreads();   // the only block barrier

  for (int rt = w; rt < 72; rt += 4) {
    int R0 = rt * 16;
    int h = rt / 9;
    int krbase = R0 - h * 144;
    // ---- phase A: actT[n][kr] = cross x A_w^T ----
    f32x4 acc[2];
    acc[0] = (f32x4){0.f, 0.f, 0.f, 0.f};
    acc[1] = (f32x4){0.f, 0.f, 0.f, 0.f};
    const unsigned short* Abase = A_bf + (size_t)(R0 + col) * 192 + quad * 8;
    #pragma unroll
    for (int ks = 0; ks < 6; ++ks) {
      bf16x8 wf = *(const bf16x8*)(Abase + ks * 32);   // B-operand: nn=kr rows
      acc[0] = __builtin_amdgcn_mfma_f32_16x16x32_bf16(Afr[0][ks], wf, acc[0], 0, 0, 0);
      acc[1] = __builtin_amdgcn_mfma_f32_16x16x32_bf16(Afr[1][ks], wf, acc[1], 0, 0, 0);
    }
    // ---- softmax over n = rows (in-lane 4 + quads via shfl 16/32) ----
    #pragma unroll
    for (int p = 0; p < 2; ++p) {
      float v0 = acc[p][0], v1 = acc[p][1], v2 = acc[p][2], v3 = acc[p][3];
      float mx = fmaxf(fmaxf(v0, v1), fmaxf(v2, v3));
      mx = fmaxf(mx, __shfl_xor(mx, 16));
      mx = fmaxf(mx, __shfl_xor(mx, 32));
      float e0 = __expf(v0 - mx), e1 = __expf(v1 - mx);
      float e2 = __expf(v2 - mx), e3 = __expf(v3 - mx);
      float s = (e0 + e1) + (e2 + e3);
      s += __shfl_xor(s, 16);
      s += __shfl_xor(s, 32);
      float inv = __builtin_amdgcn_rcpf(s);
      // lane holds n = quad*4..quad*4+3 for kr = col: packed contiguous store
      uint2 pk;
      pk.x = pack2(e0 * inv, e1 * inv);
      pk.y = pack2(e2 * inv, e3 * inv);
      *(uint2*)&act_bs[w][p][col][quad * 4] = pk;
    }
    asm volatile("s_waitcnt lgkmcnt(0)" ::: "memory");
    // ---- phase B: nfmT[ci][kr] = crossT x act^T (K=32, n zero-padded) ----
    int row0 = h * 24 + col;
    int row1 = min(h * 24 + 16 + col, 191);
    #pragma unroll
    for (int p = 0; p < 2; ++p) {
      bf16x8 bv = *(const bf16x8*)&act_bs[w][p][col][quad * 8];   // B-op: nn=kr
      bf16x8 a0 = *(const bf16x8*)&crossT[p][row0][quad * 8];     // A-op: m=ci 0..15
      bf16x8 a1 = *(const bf16x8*)&crossT[p][row1][quad * 8];     // A-op: m=ci 16..23
      f32x4 o0 = (f32x4){0.f, 0.f, 0.f, 0.f}, o1 = o0;
      o0 = __builtin_amdgcn_mfma_f32_16x16x32_bf16(a0, bv, o0, 0, 0, 0);
      o1 = __builtin_amdgcn_mfma_f32_16x16x32_bf16(a1, bv, o1, 0, 0, 0);
      // lane: kr=col, ci = quad*4+r (consecutive) -> packed uint2 stores
      uint2 s0;
      s0.x = pack2(o0[0], o0[1]);
      s0.y = pack2(o0[2], o0[3]);
      *(uint2*)&stg[w][p][col][quad * 4] = s0;
      if (quad < 2) {
        uint2 s1;
        s1.x = pack2(o1[0], o1[1]);
        s1.y = pack2(o1[2], o1[3]);
        *(uint2*)&stg[w][p][col][16 + quad * 4] = s1;
      }
    }
    asm volatile("s_waitcnt lgkmcnt(0)" ::: "memory");
    // ---- cooperative 768B-contiguous writes ----
    if (lane < 48) {
      #pragma unroll
      for (int p = 0; p < 2; ++p) {
        uint4 v = ((const uint4*)&stg[w][p][0][0])[lane];
        uint4* gdst = (uint4*)(nfm + ((((size_t)(p0 + p) * 8 + h) * 144 + krbase) * 24));
        gdst[lane] = v;
      }
    }
  }
}

// ---------- k3: MFMA feat GEMMs + center -> ka12[r][d][p] ----------
// one wave per block; nfm layout [p][h][144][24]
__global__ __launch_bounds__(64) void k3_feat(
    const unsigned short* __restrict__ W2bf,
    const unsigned short* __restrict__ Wcbf,
    const unsigned short* __restrict__ fmTbf,
    const unsigned short* __restrict__ nfm,
    float* __restrict__ ka12, int V) {
  int pb = blockIdx.x, r = blockIdx.y;
  int lane = threadIdx.x;
  int quad = lane >> 4, col = lane & 15;
  int p0 = pb * 32;
  f32x4 acc[4][2];
  #pragma unroll
  for (int m = 0; m < 4; ++m)
    #pragma unroll
    for (int j = 0; j < 2; ++j) acc[m][j] = (f32x4){0.f, 0.f, 0.f, 0.f};

  int base24[6];
  #pragma unroll
  for (int ks = 0; ks < 6; ++ks) {
    int ci = ks * 32 + quad * 8;
    int hh = ci / 24, oo = ci - hh * 24;
    base24[ks] = hh * 3456 + oo;   // h*144*24 + off
  }

  const unsigned short* Bn0 = nfm + (size_t)(p0 + col) * 27648;
  const unsigned short* Bn1 = nfm + (size_t)(p0 + 16 + col) * 27648;
  const unsigned short* Bc0 = fmTbf + (size_t)(p0 + col) * 192;
  const unsigned short* Bc1 = fmTbf + (size_t)(p0 + 16 + col) * 192;

  for (int kb = 0; kb < 13; ++kb) {
    const unsigned short* Ab;
    if (kb < 12) Ab = W2bf + (size_t)(kb * 12 + r) * (64 * 192);
    else         Ab = Wcbf + (size_t)r * (64 * 192);
    int kr24 = (kb * 12 + r) * 24;
    #pragma unroll
    for (int ks = 0; ks < 6; ++ks) {
      int ko = ks * 32 + quad * 8;
      bf16x8 b0, b1;
      if (kb < 12) {
        b0 = *(const bf16x8*)(Bn0 + base24[ks] + kr24);
        b1 = *(const bf16x8*)(Bn1 + base24[ks] + kr24);
      } else {
        b0 = *(const bf16x8*)(Bc0 + ko);
        b1 = *(const bf16x8*)(Bc1 + ko);
      }
      #pragma unroll
      for (int m = 0; m < 4; ++m) {
        bf16x8 a = *(const bf16x8*)(Ab + (size_t)(m * 16 + col) * 192 + ko);
        acc[m][0] = __builtin_amdgcn_mfma_f32_16x16x32_bf16(a, b0, acc[m][0], 0, 0, 0);
        acc[m][1] = __builtin_amdgcn_mfma_f32_16x16x32_bf16(a, b1, acc[m][1], 0, 0, 0);
      }
    }
  }
  #pragma unroll
  for (int m = 0; m < 4; ++m) {
    #pragma unroll
    for (int rr = 0; rr < 4; ++rr) {
      int d = m * 16 + quad * 4 + rr;
      float* dst = &ka12[(size_t)(r * 64 + d) * V + p0 + col];
      dst[0]  = acc[m][0][rr];
      dst[16] = acc[m][1][rr];
    }
  }
}

// ---------- k4: c2v max -> ka output ----------
__global__ __launch_bounds__(256) void k4_final(
    const float* __restrict__ ka12, float* __restrict__ out, int V) {
  int idx = blockIdx.x * 256 + threadIdx.x;
  int total = DO * V * 6;
  if (idx >= total) return;
  int j = idx % 6, rem = idx / 6;
  int p = rem % V, d = rem / V;
  size_t base = (size_t)d * V + p;
  float a = ka12[(size_t)c_C2V[j][0] * 64 * V + base];
  float b = ka12[(size_t)c_C2V[j][1] * 64 * V + base];
  out[idx] = fmaxf(a, b);
}

// ---------- host ----------
extern "C" void kernel_launch(void* const* d_in, const int* in_sizes, int n_in,
                              void* d_out, int out_size, void* d_ws, size_t ws_size,
                              hipStream_t stream) {
  const int* nbi = (const int*)d_in[0];
  const float* verts = (const float*)d_in[1];
  const float* fm = (const float*)d_in[2];
  const float* Wdim = (const float*)d_in[3];
  const float* W = (const float*)d_in[4];
  const float* Wdir = (const float*)d_in[5];
  float* out = (float*)d_out;
  float* ws = (float*)d_ws;
  int V = in_sizes[0] / NN;   // 2048

  unsigned short* A_bf  = (unsigned short*)ws;             // 221184 ush
  unsigned short* W2bf  = (unsigned short*)(ws + 110592);  // 1769472 ush
  unsigned short* Wcbf  = (unsigned short*)(ws + 995328);  // 147456 ush
  unsigned short* fmTbf = (unsigned short*)(ws + 1069056); // 192*V ush
  size_t o = 1069056 + (size_t)96 * V;
  unsigned short* cross_bf = (unsigned short*)(ws + o);    // 3072*V ush
  o += (size_t)1536 * V;
  float* ka12 = ws + o;                                    // 768*V f32
  o += (size_t)768 * V;
  unsigned short* nfm = (unsigned short*)(ws + o);         // 27648*V ush  [p][h][144][24]

  int n0 = 2138112 + 192 * V;
  k0_expand<<<(n0 + 255) / 256, 256, 0, stream>>>(W, Wdir, fm, A_bf, W2bf, Wcbf, fmTbf,
                                                  out + (size_t)DO * V * 6, V);
  k1_cross<<<V, 256, 0, stream>>>(nbi, verts, fm, Wdim, cross_bf, V);
  k2_main<<<V / 2, 256, 0, stream>>>(A_bf, cross_bf, nfm, V);
  k3_feat<<<dim3(V / 32, 12), 64, 0, stream>>>(W2bf, Wcbf, fmTbf, nfm, ka12, V);
  k4_final<<<(DO * V * 6 + 255) / 256, 256, 0, stream>>>(ka12, out, V);
}

// Round 6
// 186.884 us; speedup vs baseline: 5.0752x; 1.4223x over previous
//
#include <hip/hip_runtime.h>
#include <cstdint>
#include <cstddef>

#define NN 16   // neighbors
#define DI 32
#define DO 64

typedef short bf16x8 __attribute__((ext_vector_type(8)));
typedef float f32x4 __attribute__((ext_vector_type(4)));

// ---------- tables ----------
__device__ __constant__ int c_INV[12][6] = {
  {0,1,2,3,4,5},{0,5,4,3,2,1},{4,3,0,5,2,1},{1,2,4,3,5,0},
  {3,5,2,0,4,1},{1,4,3,5,0,2},{4,0,3,1,2,5},{1,0,2,4,3,5},
  {4,1,2,5,0,3},{3,1,4,0,2,5},{2,1,4,5,3,0},{4,5,0,3,1,2}};
__device__ __constant__ int c_ROLL[5][6] = {
  {0,1,2,3,4,5},{0,2,3,4,5,1},{0,3,4,5,1,2},{0,4,5,1,2,3},{0,5,1,2,3,4}};
__device__ __constant__ float c_VS[12][3] = {
  {0.f, 0.5257311121f, 0.8506508084f},
  {0.f, 0.5257311121f, -0.8506508084f},
  {0.f, -0.5257311121f, 0.8506508084f},
  {0.f, -0.5257311121f, -0.8506508084f},
  {0.5257311121f, 0.8506508084f, 0.f},
  {0.5257311121f, -0.8506508084f, 0.f},
  {-0.5257311121f, 0.8506508084f, 0.f},
  {-0.5257311121f, -0.8506508084f, 0.f},
  {0.8506508084f, 0.f, 0.5257311121f},
  {0.8506508084f, 0.f, -0.5257311121f},
  {-0.8506508084f, 0.f, 0.5257311121f},
  {-0.8506508084f, 0.f, -0.5257311121f}};
__device__ __constant__ int c_C2V[6][2] = {{0,1},{6,7},{2,11},{4,9},{5,8},{3,10}};

// ---------- helpers ----------
__device__ inline unsigned short f2bf(float f) {
  unsigned int u = __float_as_uint(f);
  unsigned int r = (u + 0x7fffu + ((u >> 16) & 1u)) >> 16;   // RNE
  return (unsigned short)r;
}
__device__ inline float bf2f(unsigned short h) {
  return __uint_as_float(((unsigned int)h) << 16);
}
__device__ inline unsigned int pack2(float a, float b) {
  return (unsigned int)f2bf(a) | ((unsigned int)f2bf(b) << 16);
}

__device__ inline float sym13(const float* __restrict__ w, int k, int j) {
  if (k == 0)  return w[j == 0 ? 0 : 1];
  if (k == 1)  return w[j == 0 ? 2 : 3];
  if (k == 12) return w[j == 0 ? 4 : 5];
  int a = (k - 2) / 5, rr = (k - 2) % 5;
  return w[6 + a * 6 + c_ROLL[rr][j]];
}

// ---------- k0: weight expansion (k-major bf16) + fmT + passthrough ----------
// A_bf: [rt72][ks6][q4][16][8]   (row = rt*16+rl, ci = ks*32+q*8+j), scaled 0.5
// W2k : [kr144][ks6][q4][64][8]  (d rows, ci = ks*32+q*8+j)
// Wck : [r12][ks6][q4][64][8]
__global__ __launch_bounds__(256) void k0_expand(
    const float* __restrict__ W, const float* __restrict__ Wdir,
    const float* __restrict__ fm,
    unsigned short* __restrict__ A_bf,
    unsigned short* __restrict__ W2k,
    unsigned short* __restrict__ Wck,
    unsigned short* __restrict__ fmTbf,   // [V][192] bf16
    float* __restrict__ out_fm, int V) {
  int idx = blockIdx.x * 256 + threadIdx.x;
  if (idx < 221184) {
    int row = idx / 192, ci = idx % 192;
    int h = row / 144, k = (row / 12) % 12, r = row % 12;
    int c = ci / 6, i = ci % 6;
    int rt = row >> 4, rl = row & 15;
    int ks = ci >> 5, q = (ci >> 3) & 3, j = ci & 7;
    A_bf[(((rt * 6 + ks) * 4 + q) * 16 + rl) * 8 + j] =
        f2bf(0.5f * sym13(&Wdir[(h * 32 + c) * 18], k, c_INV[r][i]));
  } else if (idx < 1990656) {
    int e = idx - 221184;
    int kr = e / 12288, rem = e % 12288;
    int k = kr / 12, r = kr % 12, d = rem / 192, ci = rem % 192;
    int c = ci / 6, i = ci % 6;
    int ks = ci >> 5, q = (ci >> 3) & 3, j = ci & 7;
    W2k[kr * 12288 + ((ks * 4 + q) * 64 + d) * 8 + j] =
        f2bf(sym13(&W[(d * 32 + c) * 18], k, c_INV[r][i]));
  } else if (idx < 2138112) {
    int e = idx - 1990656;
    int r = e / 12288, rem = e % 12288, d = rem / 192, ci = rem % 192;
    int c = ci / 6, i = ci % 6;
    int ks = ci >> 5, q = (ci >> 3) & 3, j = ci & 7;
    Wck[r * 12288 + ((ks * 4 + q) * 64 + d) * 8 + j] =
        f2bf(sym13(&W[(d * 32 + c) * 18], 12, c_INV[r][i]));
  } else {
    int e = idx - 2138112;
    if (e < 192 * V) {
      int p = e / 192, ci = e % 192, c = ci / 6, i = ci % 6;
      float v = fm[(c * V + p) * 6 + i];
      fmTbf[e] = f2bf(v);
      out_fm[(c * V + p) * 6 + i] = v;
    }
  }
}

// ---------- k1: directions + de6 + W_dim -> cross_n [p][n][ci] + crossT_g [p][ci][n] ----------
__global__ __launch_bounds__(256) void k1_cross(
    const int* __restrict__ nbi, const float* __restrict__ verts,
    const float* __restrict__ fm, const float* __restrict__ Wdim,
    unsigned short* __restrict__ cross_n,
    unsigned short* __restrict__ crossT_g, int V) {
  __shared__ float in_s[NN * 33 * 6];
  __shared__ float wd_s[33 * 32];
  __shared__ unsigned int cross_u[1536];   // [n][ci2] packed bf16 pairs
  __shared__ int nb_s[NN];
  int p = blockIdx.x, t = threadIdx.x;
  if (t < NN) nb_s[t] = nbi[p * NN + t];
  for (int idx = t; idx < 1056; idx += 256) wd_s[idx] = Wdim[idx];
  __syncthreads();
  for (int idx = t; idx < NN * 32 * 6; idx += 256) {
    int n = idx / 192, rest = idx % 192, c = rest / 6, i = rest % 6;
    in_s[(n * 33 + c) * 6 + i] = fm[(c * V + nb_s[n]) * 6 + i];
  }
  if (t < NN) {
    int n = t, nb = nb_s[n];
    float px = verts[p * 3 + 0], py = verts[p * 3 + 1], pz = verts[p * 3 + 2];
    float dx = verts[nb * 3 + 0] - px, dy = verts[nb * 3 + 1] - py, dz = verts[nb * 3 + 2] - pz;
    float L = sqrtf(dx * dx + dy * dy + dz * dz);
    float inv = 1.0f / fmaxf(L, 1e-12f);
    dx *= inv; dy *= inv; dz *= inv;
    float de[12];
    #pragma unroll
    for (int v = 0; v < 12; ++v)
      de[v] = c_VS[v][0] * dx + c_VS[v][1] * dy + c_VS[v][2] * dz;
    #pragma unroll
    for (int j = 0; j < 6; ++j)
      in_s[(n * 33 + 32) * 6 + j] = fmaxf(de[c_C2V[j][0]], de[c_C2V[j][1]]);
  }
  __syncthreads();
  for (int idx = t; idx < 1536; idx += 256) {
    int n = idx / 96, cp2 = idx % 96;
    int ci0 = cp2 * 2, ci1 = ci0 + 1;
    int o0 = ci0 / 6, i0 = ci0 % 6;
    int o1 = ci1 / 6, i1 = ci1 % 6;
    float s0 = 0.f, s1 = 0.f;
    #pragma unroll
    for (int c = 0; c <= 32; ++c) {
      float f0 = in_s[(n * 33 + c) * 6 + i0];
      float f1 = in_s[(n * 33 + c) * 6 + i1];
      s0 = fmaf(wd_s[c * 32 + o0], f0, s0);
      s1 = fmaf(wd_s[c * 32 + o1], f1, s1);
    }
    cross_u[idx] = (unsigned int)f2bf(s0) | ((unsigned int)f2bf(s1) << 16);
  }
  __syncthreads();
  // layout 1: [n][ci] straight copy
  {
    const uint4* src = (const uint4*)cross_u;
    uint4* d1 = (uint4*)(cross_n + (size_t)p * 3072);
    for (int idx = t; idx < 384; idx += 256) d1[idx] = src[idx];
  }
  // layout 2: [ci][n] transpose (np slow-varying to keep LDS reads conflict-free)
  {
    unsigned int* d2 = (unsigned int*)(crossT_g + (size_t)p * 3072);
    for (int idx = t; idx < 1536; idx += 256) {
      int np = idx / 192, ci = idx % 192;
      unsigned int u0 = cross_u[(2 * np) * 96 + (ci >> 1)];
      unsigned int u1 = cross_u[(2 * np + 1) * 96 + (ci >> 1)];
      unsigned int h0 = (ci & 1) ? (u0 >> 16) : (u0 & 0xffffu);
      unsigned int h1 = (ci & 1) ? (u1 & 0xffff0000u) : (u1 << 16);
      d2[ci * 8 + np] = h0 | h1;
    }
  }
}

// ---------- k2: MFMA act GEMM + row-softmax + shfl-redistribute + MFMA nfm ----------
// 2 vertices/block, 4 waves. LDS = crossT only (30720 B) -> 4 blocks/CU resident.
// Barrier-free K-loop: act moves via 4 shfls/p (no LDS), nfm written direct to global.
__global__ __launch_bounds__(256, 4) void k2_main(
    const unsigned short* __restrict__ A_bf,      // k-major
    const unsigned short* __restrict__ cross_n,   // [p][n][ci]
    const unsigned short* __restrict__ crossT_g,  // [p][ci][n]
    unsigned short* __restrict__ nfm, int V) {
  __shared__ __align__(16) unsigned short crossT[2][192][40];  // [p][ci][n], n 16..31 zero
  int t = threadIdx.x;
  int w = t >> 6, lane = t & 63;
  int quad = lane >> 4, col = lane & 15;
  int p0 = blockIdx.x * 2;

  // phase-A A-operand frags (cross, m=n): tile-invariant
  bf16x8 Afr[2][6];
  #pragma unroll
  for (int p = 0; p < 2; ++p)
    #pragma unroll
    for (int ks = 0; ks < 6; ++ks)
      Afr[p][ks] = *(const bf16x8*)(cross_n + (size_t)(p0 + p) * 3072 + col * 192 + ks * 32 + quad * 8);

  // stage crossT cols 0..15 from global; zero cols 16..31
  for (int idx = t; idx < 768; idx += 256) {
    int p = idx / 384, rem = idx % 384, ci = rem >> 1, half = rem & 1;
    *(uint4*)&crossT[p][ci][half * 8] =
        *(const uint4*)(crossT_g + (size_t)(p0 + p) * 3072 + ci * 16 + half * 8);
  }
  for (int idx = t; idx < 768; idx += 256) {
    int p = idx / 384, rem = idx % 384, ci = rem >> 1, half = rem & 1;
    *(uint4*)&crossT[p][ci][16 + half * 8] = make_uint4(0u, 0u, 0u, 0u);
  }
  __syncthreads();   // the only barrier

  int s0l = quad * 32 + col;   // shfl sources (meaningful for quad<2)
  int s1l = s0l + 16;

  for (int rt = w; rt < 72; rt += 4) {
    int h = rt / 9;
    int krbase = rt * 16 - h * 144;
    // ---- phase A: actT[n][kr] ----
    f32x4 acc[2];
    acc[0] = (f32x4){0.f, 0.f, 0.f, 0.f};
    acc[1] = (f32x4){0.f, 0.f, 0.f, 0.f};
    const unsigned short* Abase = A_bf + rt * 3072 + quad * 128 + col * 8;
    #pragma unroll
    for (int ks = 0; ks < 6; ++ks) {
      bf16x8 wf = *(const bf16x8*)(Abase + ks * 512);
      acc[0] = __builtin_amdgcn_mfma_f32_16x16x32_bf16(Afr[0][ks], wf, acc[0], 0, 0, 0);
      acc[1] = __builtin_amdgcn_mfma_f32_16x16x32_bf16(Afr[1][ks], wf, acc[1], 0, 0, 0);
    }
    int row0 = h * 24 + col;
    int row1 = min(h * 24 + 16 + col, 191);
    #pragma unroll
    for (int p = 0; p < 2; ++p) {
      // ---- softmax over n = rows ----
      float v0 = acc[p][0], v1 = acc[p][1], v2 = acc[p][2], v3 = acc[p][3];
      float mx = fmaxf(fmaxf(v0, v1), fmaxf(v2, v3));
      mx = fmaxf(mx, __shfl_xor(mx, 16));
      mx = fmaxf(mx, __shfl_xor(mx, 32));
      float e0 = __expf(v0 - mx), e1 = __expf(v1 - mx);
      float e2 = __expf(v2 - mx), e3 = __expf(v3 - mx);
      float s = (e0 + e1) + (e2 + e3);
      s += __shfl_xor(s, 16);
      s += __shfl_xor(s, 32);
      float inv = __builtin_amdgcn_rcpf(s);
      unsigned int lo = pack2(e0 * inv, e1 * inv);
      unsigned int hi = pack2(e2 * inv, e3 * inv);
      // ---- redistribute act (C layout) -> B-operand layout via shfl ----
      unsigned int b0 = (unsigned int)__shfl((int)lo, s0l);
      unsigned int b1 = (unsigned int)__shfl((int)hi, s0l);
      unsigned int b2 = (unsigned int)__shfl((int)lo, s1l);
      unsigned int b3 = (unsigned int)__shfl((int)hi, s1l);
      bool vq = (quad < 2);
      union { uint4 u; bf16x8 v; } cvt;
      cvt.u = make_uint4(vq ? b0 : 0u, vq ? b1 : 0u, vq ? b2 : 0u, vq ? b3 : 0u);
      bf16x8 bv = cvt.v;
      // ---- phase B: nfmT[ci][kr] (K=32, n zero-padded) ----
      bf16x8 a0 = *(const bf16x8*)&crossT[p][row0][quad * 8];
      bf16x8 a1 = *(const bf16x8*)&crossT[p][row1][quad * 8];
      f32x4 o0 = (f32x4){0.f, 0.f, 0.f, 0.f}, o1 = o0;
      o0 = __builtin_amdgcn_mfma_f32_16x16x32_bf16(a0, bv, o0, 0, 0, 0);
      o1 = __builtin_amdgcn_mfma_f32_16x16x32_bf16(a1, bv, o1, 0, 0, 0);
      // ---- direct global stores: row (p,h,krbase+col), cols quad*4.. ----
      size_t rowbase = (((size_t)(p0 + p) * 8 + h) * 144 + krbase + col) * 24;
      uint2 w0;
      w0.x = pack2(o0[0], o0[1]);
      w0.y = pack2(o0[2], o0[3]);
      *(uint2*)(nfm + rowbase + quad * 4) = w0;
      if (quad < 2) {
        uint2 w1;
        w1.x = pack2(o1[0], o1[1]);
        w1.y = pack2(o1[2], o1[3]);
        *(uint2*)(nfm + rowbase + 16 + quad * 4) = w1;
      }
    }
  }
}

// ---------- k3: MFMA feat GEMMs + center, 4-wave K-split + LDS reduce ----------
// grid (V/32, 12) x 256 threads -> 3072 waves (12/CU). nfm layout [p][h][144][24].
__global__ __launch_bounds__(256) void k3_feat(
    const unsigned short* __restrict__ W2k,
    const unsigned short* __restrict__ Wck,
    const unsigned short* __restrict__ fmTbf,
    const unsigned short* __restrict__ nfm,
    float* __restrict__ ka12, int V) {
  __shared__ float red[3][32][64];   // 24576 B
  int pb = blockIdx.x, r = blockIdx.y;
  int t = threadIdx.x, w = t >> 6, lane = t & 63;
  int quad = lane >> 4, col = lane & 15;
  int p0 = pb * 32;
  f32x4 acc[4][2];
  #pragma unroll
  for (int m = 0; m < 4; ++m)
    #pragma unroll
    for (int j = 0; j < 2; ++j) acc[m][j] = (f32x4){0.f, 0.f, 0.f, 0.f};

  int base24[6];
  #pragma unroll
  for (int ks = 0; ks < 6; ++ks) {
    int ci = ks * 32 + quad * 8;
    int hh = ci / 24, oo = ci - hh * 24;
    base24[ks] = hh * 3456 + oo;   // h*144*24 + off
  }

  const unsigned short* Bn0 = nfm + (size_t)(p0 + col) * 27648;
  const unsigned short* Bn1 = nfm + (size_t)(p0 + 16 + col) * 27648;
  const unsigned short* Bc0 = fmTbf + (size_t)(p0 + col) * 192;
  const unsigned short* Bc1 = fmTbf + (size_t)(p0 + 16 + col) * 192;

  int nkb = (w == 3) ? 4 : 3;
  for (int i = 0; i < nkb; ++i) {
    int kb = w * 3 + i;   // w=3,i=3 -> 12 (center)
    const unsigned short* Ab;
    int kr24 = 0;
    if (kb < 12) { Ab = W2k + (size_t)(kb * 12 + r) * 12288; kr24 = (kb * 12 + r) * 24; }
    else         { Ab = Wck + (size_t)r * 12288; }
    const unsigned short* Albase = Ab + quad * 512 + col * 8;
    #pragma unroll
    for (int ks = 0; ks < 6; ++ks) {
      bf16x8 b0, b1;
      if (kb < 12) {
        b0 = *(const bf16x8*)(Bn0 + base24[ks] + kr24);
        b1 = *(const bf16x8*)(Bn1 + base24[ks] + kr24);
      } else {
        int ko = ks * 32 + quad * 8;
        b0 = *(const bf16x8*)(Bc0 + ko);
        b1 = *(const bf16x8*)(Bc1 + ko);
      }
      #pragma unroll
      for (int m = 0; m < 4; ++m) {
        bf16x8 a = *(const bf16x8*)(Albase + ks * 2048 + m * 128);
        acc[m][0] = __builtin_amdgcn_mfma_f32_16x16x32_bf16(a, b0, acc[m][0], 0, 0, 0);
        acc[m][1] = __builtin_amdgcn_mfma_f32_16x16x32_bf16(a, b1, acc[m][1], 0, 0, 0);
      }
    }
  }
  // K-split reduction
  if (w > 0) {
    #pragma unroll
    for (int m = 0; m < 4; ++m)
      #pragma unroll
      for (int j = 0; j < 2; ++j)
        #pragma unroll
        for (int rr = 0; rr < 4; ++rr)
          red[w - 1][m * 8 + j * 4 + rr][lane] = acc[m][j][rr];
  }
  __syncthreads();
  if (w == 0) {
    #pragma unroll
    for (int m = 0; m < 4; ++m)
      #pragma unroll
      for (int j = 0; j < 2; ++j)
        #pragma unroll
        for (int rr = 0; rr < 4; ++rr) {
          int ri = m * 8 + j * 4 + rr;
          acc[m][j][rr] += red[0][ri][lane] + red[1][ri][lane] + red[2][ri][lane];
        }
    #pragma unroll
    for (int m = 0; m < 4; ++m) {
      #pragma unroll
      for (int rr = 0; rr < 4; ++rr) {
        int d = m * 16 + quad * 4 + rr;
        float* dst = &ka12[(size_t)(r * 64 + d) * V + p0 + col];
        dst[0]  = acc[m][0][rr];
        dst[16] = acc[m][1][rr];
      }
    }
  }
}

// ---------- k4: c2v max -> ka output ----------
__global__ __launch_bounds__(256) void k4_final(
    const float* __restrict__ ka12, float* __restrict__ out, int V) {
  int idx = blockIdx.x * 256 + threadIdx.x;
  int total = DO * V * 6;
  if (idx >= total) return;
  int j = idx % 6, rem = idx / 6;
  int p = rem % V, d = rem / V;
  size_t base = (size_t)d * V + p;
  float a = ka12[(size_t)c_C2V[j][0] * 64 * V + base];
  float b = ka12[(size_t)c_C2V[j][1] * 64 * V + base];
  out[idx] = fmaxf(a, b);
}

// ---------- host ----------
extern "C" void kernel_launch(void* const* d_in, const int* in_sizes, int n_in,
                              void* d_out, int out_size, void* d_ws, size_t ws_size,
                              hipStream_t stream) {
  const int* nbi = (const int*)d_in[0];
  const float* verts = (const float*)d_in[1];
  const float* fm = (const float*)d_in[2];
  const float* Wdim = (const float*)d_in[3];
  const float* W = (const float*)d_in[4];
  const float* Wdir = (const float*)d_in[5];
  float* out = (float*)d_out;
  float* ws = (float*)d_ws;
  int V = in_sizes[0] / NN;   // 2048

  unsigned short* A_bf  = (unsigned short*)ws;             // 221184 ush
  unsigned short* W2k   = (unsigned short*)(ws + 110592);  // 1769472 ush
  unsigned short* Wck   = (unsigned short*)(ws + 995328);  // 147456 ush
  unsigned short* fmTbf = (unsigned short*)(ws + 1069056); // 192*V ush
  size_t o = 1069056 + (size_t)96 * V;
  unsigned short* cross_n = (unsigned short*)(ws + o);     // 3072*V ush [p][n][ci]
  o += (size_t)1536 * V;
  unsigned short* crossT_g = (unsigned short*)(ws + o);    // 3072*V ush [p][ci][n]
  o += (size_t)1536 * V;
  float* ka12 = ws + o;                                    // 768*V f32
  o += (size_t)768 * V;
  unsigned short* nfm = (unsigned short*)(ws + o);         // 27648*V ush [p][h][144][24]

  int n0 = 2138112 + 192 * V;
  k0_expand<<<(n0 + 255) / 256, 256, 0, stream>>>(W, Wdir, fm, A_bf, W2k, Wck, fmTbf,
                                                  out + (size_t)DO * V * 6, V);
  k1_cross<<<V, 256, 0, stream>>>(nbi, verts, fm, Wdim, cross_n, crossT_g, V);
  k2_main<<<V / 2, 256, 0, stream>>>(A_bf, cross_n, crossT_g, nfm, V);
  k3_feat<<<dim3(V / 32, 12), 256, 0, stream>>>(W2k, Wck, fmTbf, nfm, ka12, V);
  k4_final<<<(DO * V * 6 + 255) / 256, 256, 0, stream>>>(ka12, out, V);
}